// Round 14
// baseline (410.325 us; speedup 1.0000x reference)
//
#include <hip/hip_runtime.h>
#include <cstddef>

constexpr int V = 50000, E = 400000, R = 400, D = 100, OUT = 200, B = 1024;
constexpr int HALF = E / 2;
constexpr float EPS = 1e-5f;
constexpr int K2 = 232;        // obj K pad (bf16)
constexpr int VPAD = 50176;    // 196*256
constexpr int NTILE = VPAD / 16;  // 3136 v-tiles for packed emb
constexpr int NKEY = 800;      // (rel, side)
constexpr int E1MAX = 450560;  // E + NKEY*63 rounded up; /64 = 7040 chunks
constexpr int MT_O = 208, MT_K = 128;
constexpr int MT_SZ = MT_O * MT_K;
constexpr int NB2 = 196;       // coarse dst buckets (dst>>8)
constexpr int BCAP = 2560;     // bucket capacity
constexpr int ECHK = 8;        // chunks per edgemm block; 7040/8=880 (div 8)

typedef short bf16x8 __attribute__((ext_vector_type(8)));
typedef float f32x4  __attribute__((ext_vector_type(4)));
typedef unsigned short ushort8 __attribute__((ext_vector_type(8)));
typedef __attribute__((address_space(1))) const unsigned int guint_t;
typedef __attribute__((address_space(3))) unsigned int luint_t;

__device__ inline unsigned short f2bf(float x) {
    unsigned u = __float_as_uint(x);
    u = (u + 0x7fffu + ((u >> 16) & 1u)) >> 16;
    return (unsigned short)u;
}
__device__ inline float bf2f(unsigned short u) {
    return __uint_as_float(((unsigned)u) << 16);
}

// ---------------- fused precompute + key-hist: Mloop | r_out | WT_bf | ent_bf | hist1
constexpr int G_MLOOP = (D * OUT + 255) / 256;       // 79
constexpr int G_ROUT  = (R * OUT + 255) / 256;       // 313
constexpr int G_CVTWT = (2 * 208 * 16) / 256;        // 26
constexpr int G_CVTENT = (V * 16) / 256;             // 3125
constexpr int G_HIST = 512;
constexpr int PRE_B1 = G_MLOOP;
constexpr int PRE_B2 = PRE_B1 + G_ROUT;
constexpr int PRE_B3 = PRE_B2 + G_CVTWT;
constexpr int PRE_B4 = PRE_B3 + G_CVTENT;
constexpr int PRE_NWG = PRE_B4 + G_HIST;

__global__ __launch_bounds__(256) void k_pre(const float* __restrict__ loop_rel,
                                             const float* __restrict__ loop_w,
                                             const float* __restrict__ rel_emb,
                                             const float* __restrict__ w_rel,
                                             const float* __restrict__ in_w,
                                             const float* __restrict__ out_w,
                                             const float* __restrict__ ent_emb,
                                             const int* __restrict__ etyp,
                                             float* __restrict__ Mloop,
                                             float* __restrict__ r_out,
                                             unsigned short* __restrict__ WT_bf,
                                             unsigned short* __restrict__ ent_bf,
                                             int* __restrict__ hist1) {
    __shared__ int lh[NKEY];
    int blk = blockIdx.x, t = threadIdx.x;
    if (blk < PRE_B1) {
        int i = blk * 256 + t;
        if (i >= D * OUT) return;
        int j = i / OUT, o = i % OUT;
        float s = 0.f;
        for (int k = 0; k < D; ++k) {
            int idx = j + k; if (idx >= D) idx -= D;
            s += loop_rel[idx] * loop_w[k * OUT + o];
        }
        Mloop[i] = s;
    } else if (blk < PRE_B2) {
        int i = (blk - PRE_B1) * 256 + t;
        if (i >= R * OUT) return;
        int r = i / OUT, o = i % OUT;
        float s = 0.f;
        for (int k = 0; k < D; ++k) s += rel_emb[r * D + k] * w_rel[k * OUT + o];
        r_out[i] = s;
    } else if (blk < PRE_B3) {
        int i = (blk - PRE_B2) * 256 + t;
        int side = i / (208 * 16);
        int rem = i - side * 208 * 16;
        int o = rem >> 4, c8 = rem & 15;
        int k0 = c8 * 8;
        const float* __restrict__ W = side ? out_w : in_w;
        ushort8 v = (ushort8)0;
        if (o < 200) {
#pragma unroll
            for (int q = 0; q < 8; ++q) {
                int k = k0 + q;
                if (k < 100) v[q] = f2bf(W[k * OUT + o]);
            }
        }
        *(ushort8*)&WT_bf[((size_t)side * 208 + o) * 128 + k0] = v;
    } else if (blk < PRE_B4) {
        int i = (blk - PRE_B3) * 256 + t;
        if (i >= V * 16) return;
        int v = i >> 4, c8 = i & 15;
        int c0 = c8 * 8;
        ushort8 o = (ushort8)0;
        if (c0 < 96) {
            float4 f0 = *(const float4*)&ent_emb[(size_t)v * D + c0];
            float4 f1 = *(const float4*)&ent_emb[(size_t)v * D + c0 + 4];
            o[0] = f2bf(f0.x); o[1] = f2bf(f0.y); o[2] = f2bf(f0.z); o[3] = f2bf(f0.w);
            o[4] = f2bf(f1.x); o[5] = f2bf(f1.y); o[6] = f2bf(f1.z); o[7] = f2bf(f1.w);
        } else if (c0 == 96) {
            float4 f0 = *(const float4*)&ent_emb[(size_t)v * D + 96];
            o[0] = f2bf(f0.x); o[1] = f2bf(f0.y); o[2] = f2bf(f0.z); o[3] = f2bf(f0.w);
        }
        *(ushort8*)&ent_bf[(size_t)v * 128 + c0] = o;
    } else {                                  // key histogram (LDS-aggregated)
        int hb = blk - PRE_B4;
        for (int i = t; i < NKEY; i += 256) lh[i] = 0;
        __syncthreads();
        for (int e = hb * 256 + t; e < E; e += G_HIST * 256) {
            int key = etyp[e] + (e < HALF ? 0 : R);
            atomicAdd(&lh[key], 1);
        }
        __syncthreads();
        for (int i = t; i < NKEY; i += 256) {
            int c = lh[i];
            if (c) atomicAdd(&hist1[i], c);
        }
    }
}

// ---------------- key scan (64-aligned buckets) + perm1 pad-tail fill
__global__ __launch_bounds__(1024) void k_scan(const int* __restrict__ hist1,
                                               int* __restrict__ start1,
                                               int* __restrict__ Edev,
                                               unsigned* __restrict__ perm1) {
    __shared__ int buf[1024];
    int t = threadIdx.x;
    int h = (t < NKEY) ? hist1[t] : 0;
    int c = (h + 63) & ~63;
    buf[t] = c; __syncthreads();
    for (int off = 1; off < 1024; off <<= 1) {
        int x = (t >= off) ? buf[t - off] : 0; __syncthreads();
        buf[t] += x; __syncthreads();
    }
    int s = buf[t] - c;
    if (t < NKEY) {
        start1[t] = s;
        for (int i = h; i < c; ++i) perm1[s + i] = 0xFFFFFFFFu;  // sentinel pad tail
    }
    if (t == NKEY - 1) { start1[NKEY] = buf[t]; *Edev = buf[t]; }
}

// ---------------- fused binning: perm1 scatter + dst pairs in ONE pass
__global__ __launch_bounds__(1024) void k_bin(const int* __restrict__ etyp,
                                              const int* __restrict__ edst,
                                              const int* __restrict__ start1,
                                              int* __restrict__ cursor1,
                                              int* __restrict__ cursor196,
                                              unsigned* __restrict__ perm1,
                                              uint2* __restrict__ pairs) {
    __shared__ int lhist[NKEY], lbase[NKEY], lcnt[NKEY];
    __shared__ int chist[NB2], cbase[NB2], ccnt[NB2];
    int t = threadIdx.x;
    int e0 = blockIdx.x * 8192;
    for (int i = t; i < NKEY; i += 1024) { lhist[i] = 0; lcnt[i] = 0; }
    for (int i = t; i < NB2; i += 1024) { chist[i] = 0; ccnt[i] = 0; }
    __syncthreads();
    for (int i = t; i < 8192; i += 1024) {
        int e = e0 + i;
        if (e < E) {
            int key = etyp[e] + (e < HALF ? 0 : R);
            atomicAdd(&lhist[key], 1);
            atomicAdd(&chist[edst[e] >> 8], 1);
        }
    }
    __syncthreads();
    for (int i = t; i < NKEY; i += 1024) {
        int c = lhist[i];
        lbase[i] = c ? (start1[i] + atomicAdd(&cursor1[i], c)) : 0;
    }
    for (int i = t; i < NB2; i += 1024) {
        int c = chist[i];
        cbase[i] = c ? atomicAdd(&cursor196[i], c) : 0;
    }
    __syncthreads();
    for (int i = t; i < 8192; i += 1024) {
        int e = e0 + i;
        if (e < E) {
            int key = etyp[e] + (e < HALF ? 0 : R);
            int r = atomicAdd(&lcnt[key], 1);
            int p = lbase[key] + r;
            perm1[p] = (unsigned)e | ((unsigned)key << 19);
            int d = edst[e];
            int ld = d >> 8;
            int rr = atomicAdd(&ccnt[ld], 1);
            int slot = cbase[ld] + rr;
            if (slot < BCAP)
                pairs[(size_t)ld * BCAP + slot] = make_uint2((unsigned)d, (unsigned)p);
        }
    }
}

// ---------------- fused: per-bucket dst ranking | Mt table build (MFMA)
constexpr int BD2MT_NWG = NB2 + NKEY;   // 196 + 800

__global__ __launch_bounds__(256) void k_bd2mt(const int* __restrict__ cursor196,
                                               const uint2* __restrict__ pairs,
                                               const float* __restrict__ rel_emb,
                                               const unsigned short* __restrict__ WT_bf,
                                               int* __restrict__ start2,
                                               int* __restrict__ poslist,
                                               unsigned short* __restrict__ Mtab) {
    int blk = blockIdx.x, t = threadIdx.x;
    if (blk < NB2) {   // ---- dst ranking
        __shared__ int lcnt[256], loff[256], lrk[256], bscan[256];
        int b = blk;
        lcnt[t] = 0; lrk[t] = 0;
        bscan[t] = (t < NB2) ? min(cursor196[t], BCAP) : 0;
        __syncthreads();
        for (int off = 1; off < 256; off <<= 1) {
            int xx = (t >= off) ? bscan[t - off] : 0; __syncthreads();
            bscan[t] += xx; __syncthreads();
        }
        int base = (b > 0) ? bscan[b - 1] : 0;
        if (b == 0 && t == 0) start2[V] = bscan[NB2 - 1];
        int n = min(cursor196[b], BCAP);
        for (int i = t; i < n; i += 256) {
            int d = (int)pairs[(size_t)b * BCAP + i].x;
            atomicAdd(&lcnt[d - (b << 8)], 1);
        }
        __syncthreads();
        int cc = lcnt[t];
        loff[t] = cc; __syncthreads();
        for (int off = 1; off < 256; off <<= 1) {
            int xx = (t >= off) ? loff[t - off] : 0; __syncthreads();
            loff[t] += xx; __syncthreads();
        }
        int excl = loff[t] - cc;
        loff[t] = excl;
        int d = (b << 8) + t;
        if (d < V) start2[d] = base + excl;
        __syncthreads();
        for (int i = t; i < n; i += 256) {
            uint2 pr = pairs[(size_t)b * BCAP + i];
            int ld = (int)pr.x - (b << 8);
            int r = atomicAdd(&lrk[ld], 1);
            poslist[base + loff[ld] + r] = (int)pr.y;
        }
    } else {           // ---- Mt[key] = WT_bf[side] @ Hankel(r) via MFMA
        __shared__ unsigned short rsh[256];
        int key = blk - NB2;
        int rho = (key < R) ? key : key - R;
        int side = (key < R) ? 0 : 1;
        int lane = t & 63, wid = t >> 6;
        {
            int sm = t;
            if (sm >= 200) sm -= 200; else if (sm >= 100) sm -= 100;
            rsh[t] = f2bf(rel_emb[rho * D + sm]);
        }
        __syncthreads();
        const unsigned short* WT = WT_bf + (size_t)side * 208 * 128;
        unsigned short* MtK = Mtab + (size_t)key * MT_SZ;
        int m16 = lane & 15, kq = lane >> 4;
        for (int jt = 0; jt < 2; ++jt) {
            int j0 = (wid * 2 + jt) * 16;
            f32x4 acc[13] = {};
            for (int ks = 0; ks < 4; ++ks) {
                int rbase = ks * 32 + kq * 8 + j0 + m16;   // max 254
                ushort8 tmp;
#pragma unroll
                for (int q = 0; q < 8; ++q) tmp[q] = rsh[rbase + q];
                bf16x8 bfr = *(bf16x8*)&tmp;
#pragma unroll
                for (int of = 0; of < 13; ++of) {
                    bf16x8 afr = *(const bf16x8*)&WT[(size_t)(of * 16 + m16) * 128 + ks * 32 + kq * 8];
                    acc[of] = __builtin_amdgcn_mfma_f32_16x16x32_bf16(afr, bfr, acc[of], 0, 0, 0);
                }
            }
#pragma unroll
            for (int of = 0; of < 13; ++of) {
                int orow = of * 16 + kq * 4;
#pragma unroll
                for (int q = 0; q < 4; ++q)
                    MtK[(size_t)(orow + q) * MT_K + j0 + m16] = f2bf(acc[of][q]);
            }
        }
    }
}

// ---------------- per-chunk MFMA with Mt reuse across 8 chunks per block
__global__ __launch_bounds__(256, 2) void k_edgemm(const unsigned* __restrict__ perm1,
                                                   const int* __restrict__ Edev,
                                                   const int* __restrict__ esrc,
                                                   const float* __restrict__ enorm,
                                                   const unsigned short* __restrict__ ent_bf,
                                                   const unsigned short* __restrict__ Mtab,
                                                   unsigned short* __restrict__ msg) {
    __shared__ __align__(16) unsigned short MtL[MT_SZ];      // 53,248 B
    __shared__ __align__(16) unsigned short AtL[64 * MT_K];  // 16,384 B
    __shared__ float snrm[2][64];
    __shared__ int ssrc[2][64];
    int t = threadIdx.x, lane = t & 63, wid = t >> 6;
    int cpx = gridDim.x >> 3;
    int blk = (blockIdx.x & 7) * cpx + (blockIdx.x >> 3);
    int nE = *Edev;
    int curkey = -1;
    for (int c = 0; c < ECHK; ++c) {
        int chunk = blk * ECHK + c;
        if (chunk * 64 >= nE) break;
        int buf = c & 1;
        if (t < 64) {
            unsigned val = perm1[chunk * 64 + t];
            int e = (int)(val & 0x7FFFFu);
            bool ok = (val != 0xFFFFFFFFu);
            ssrc[buf][t] = ok ? esrc[e] : 0;
            snrm[buf][t] = ok ? enorm[e] : 0.f;
        }
        int key = (int)(perm1[chunk * 64] >> 19);   // chunk base is always real
        __syncthreads();
        if (key != curkey) {
            for (int i = 0; i < 13; ++i) {
                int G0 = (wid * 13 + i) * 64;
                int G = G0 + lane;
                int o = G >> 4, g = G & 15;
                int gs = g ^ (o & 7);
                __builtin_amdgcn_global_load_lds(
                    (guint_t*)(Mtab + (size_t)key * MT_SZ + o * MT_K + gs * 8),
                    (luint_t*)(MtL + (size_t)G0 * 8), 16, 0, 0);
            }
            curkey = key;
        }
        for (int i = 0; i < 4; ++i) {
            int base = (wid * 4 + i) * 1024;
            int Gb = base + lane * 16;
            int row = Gb >> 8;
            int g = (Gb >> 4) & 15;
            int gs = g ^ (row & 7);
            __builtin_amdgcn_global_load_lds(
                (guint_t*)(ent_bf + (size_t)ssrc[buf][row] * 128 + gs * 8),
                (luint_t*)((char*)AtL + base), 16, 0, 0);
        }
        __syncthreads();
        int erow = wid * 16 + (lane & 15);
        int kq = lane >> 4;
        f32x4 acc[13] = {};
        for (int ks = 0; ks < 4; ++ks) {
            int g = ks * 4 + kq;
            bf16x8 bfr = *(const bf16x8*)((const char*)AtL + erow * 256 + ((g ^ (erow & 7)) * 16));
#pragma unroll
            for (int of = 0; of < 13; ++of) {
                int orow = of * 16 + (lane & 15);
                bf16x8 afr = *(const bf16x8*)((const char*)MtL + orow * 256 + ((g ^ (orow & 7)) * 16));
                acc[of] = __builtin_amdgcn_mfma_f32_16x16x32_bf16(afr, bfr, acc[of], 0, 0, 0);
            }
        }
        float nr = snrm[buf][erow];
        size_t rowbase = (size_t)(chunk * 64 + erow) * OUT;
#pragma unroll
        for (int of = 0; of < 13; ++of) {
            int o0 = of * 16 + kq * 4;
            if (o0 < OUT) {
                ushort4 pk;
                pk.x = f2bf(acc[of][0] * nr); pk.y = f2bf(acc[of][1] * nr);
                pk.z = f2bf(acc[of][2] * nr); pk.w = f2bf(acc[of][3] * nr);
                *(ushort4*)&msg[rowbase + o0] = pk;
            }
        }
    }
}

// ---------------- fused gather-sum + loop-term + bias
__global__ __launch_bounds__(256) void k_aggx(const int* __restrict__ start2,
                                              const int* __restrict__ poslist,
                                              const unsigned short* __restrict__ msg,
                                              const float* __restrict__ ent_emb,
                                              const float* __restrict__ Mloop,
                                              const float* __restrict__ conv_bias,
                                              float* __restrict__ x) {
    __shared__ float xt[16][200];
    __shared__ float sat[100][20];
    int t = threadIdx.x, lane = t & 63, wid = t >> 6;
    int v0 = blockIdx.x * 16;
    int half = (lane >= 25 && lane < 50) ? 1 : 0;
    int c = lane - half * 25;
    bool act = lane < 50;
    int src = lane + 25 < 64 ? lane + 25 : 63;
    for (int i = 0; i < 4; ++i) {
        int v = v0 + wid * 4 + i;
        int s = start2[v], epos = start2[v + 1];
        float acc[8] = {};
        for (int q = s; q < epos; q += 2) {
            int qq = q + half;
            if (act && qq < epos) {
                int p = poslist[qq];
                ushort8 m = *(const ushort8*)&msg[(size_t)p * OUT + c * 8];
#pragma unroll
                for (int j = 0; j < 8; ++j) acc[j] += bf2f(m[j]);
            }
        }
#pragma unroll
        for (int j = 0; j < 8; ++j) {
            float o = __shfl(acc[j], src);
            if (lane < 25) acc[j] += o;
        }
        if (lane < 25) {
#pragma unroll
            for (int j = 0; j < 8; ++j) xt[wid * 4 + i][lane * 8 + j] = acc[j];
        }
    }
    for (int i = t; i < 400; i += 256) {
        int kg = i >> 4, vv = i & 15;
        float4 a4 = *(const float4*)&ent_emb[(size_t)(v0 + vv) * D + kg * 4];
        sat[kg * 4 + 0][vv] = a4.x;
        sat[kg * 4 + 1][vv] = a4.y;
        sat[kg * 4 + 2][vv] = a4.z;
        sat[kg * 4 + 3][vv] = a4.w;
    }
    __syncthreads();
    if (t < 200) {
        int og = t % 50, eg = t / 50;
        int o0 = og * 4, vv0 = eg * 4;
        float acc[4][4] = {};
        for (int k = 0; k < D; ++k) {
            float4 w4 = *(const float4*)&Mloop[k * OUT + o0];
            float4 ca = *(const float4*)&sat[k][vv0];
            float cc[4] = {ca.x, ca.y, ca.z, ca.w};
            float wv[4] = {w4.x, w4.y, w4.z, w4.w};
#pragma unroll
            for (int r = 0; r < 4; ++r)
#pragma unroll
                for (int j = 0; j < 4; ++j) acc[r][j] += cc[r] * wv[j];
        }
        float4 bi = *(const float4*)&conv_bias[o0];
        float bv[4] = {bi.x, bi.y, bi.z, bi.w};
#pragma unroll
        for (int r = 0; r < 4; ++r) {
            int vv = vv0 + r;
            float4 ov;
            ov.x = (xt[vv][o0 + 0] + acc[r][0]) * (1.f / 3.f) + bv[0];
            ov.y = (xt[vv][o0 + 1] + acc[r][1]) * (1.f / 3.f) + bv[1];
            ov.z = (xt[vv][o0 + 2] + acc[r][2]) * (1.f / 3.f) + bv[2];
            ov.w = (xt[vv][o0 + 3] + acc[r][3]) * (1.f / 3.f) + bv[3];
            *(float4*)&x[(size_t)(v0 + vv) * OUT + o0] = ov;
        }
    }
}

// ---------------- fused: BN stats | emb fragment-packed conversion
constexpr int G_STATS = 400;
constexpr int G_PKEMB = (NTILE * 448) / 256;    // 3136*448/256 = 5488
constexpr int STCV_NWG = G_STATS + G_PKEMB;

__global__ __launch_bounds__(256) void k_stcv(const float* __restrict__ x,
                                              const float* __restrict__ emb_ent,
                                              float* __restrict__ colsum,
                                              float* __restrict__ colsq,
                                              unsigned short* __restrict__ emb_pk) {
    int blk = blockIdx.x, t = threadIdx.x;
    if (blk < G_STATS) {
        int g = blk * 256 + t;
        int col = g % OUT;
        int r0 = g / OUT;
        float s = 0.f, sq = 0.f;
        for (int r = r0; r < V; r += 512) {
            float v = x[(size_t)r * OUT + col];
            s += v;
            sq += v * v;
        }
        atomicAdd(&colsum[col], s);
        atomicAdd(&colsq[col], sq);
    } else {
        // packed layout: chunk i = vt*448 + ks*64 + lane; holds
        // emb[vt*16 + (lane&15)][ks*32 + (lane>>4)*8 + 0..7] as bf16x8
        int i = (blk - G_STATS) * 256 + t;
        if (i >= NTILE * 448) return;
        int vt = i / 448, r = i - vt * 448;
        int lane = r & 63;
        int ks = r >> 6;
        int v = vt * 16 + (lane & 15);
        int k0 = ks * 32 + (lane >> 4) * 8;
        ushort8 o = (ushort8)0;
        if (v < V && k0 < 200) {   // k0 <= 192 here, so k0+7 <= 199: fully in-bounds
            float4 f0 = *(const float4*)&emb_ent[(size_t)v * OUT + k0];
            float4 f1 = *(const float4*)&emb_ent[(size_t)v * OUT + k0 + 4];
            o[0] = f2bf(f0.x); o[1] = f2bf(f0.y); o[2] = f2bf(f0.z); o[3] = f2bf(f0.w);
            o[4] = f2bf(f1.x); o[5] = f2bf(f1.y); o[6] = f2bf(f1.z); o[7] = f2bf(f1.w);
        }
        *(ushort8*)&emb_pk[(size_t)i * 8] = o;
    }
}

// ---------------- obj_bf (inline mean/rstd)
__global__ __launch_bounds__(256) void k_obj(const int* __restrict__ head,
                                             const int* __restrict__ rela,
                                             const float* __restrict__ x,
                                             const float* __restrict__ colsum,
                                             const float* __restrict__ colsq,
                                             const float* __restrict__ gamma,
                                             const float* __restrict__ beta,
                                             const float* __restrict__ r_out,
                                             unsigned short* __restrict__ obj_bf) {
    int b = blockIdx.x, t = threadIdx.x;
    if (t >= K2) return;
    float v = 0.f;
    if (t < OUT) {
        float m = colsum[t] / (float)V;
        float var = colsq[t] / (float)V - m * m;
        float rs = rsqrtf(var + EPS);
        int h = head[b], r = rela[b];
        float val = (x[(size_t)h * OUT + t] - m) * rs * gamma[t] + beta[t];
        val = tanhf(val);
        v = val * r_out[r * OUT + t];
    }
    obj_bf[(size_t)b * K2 + t] = f2bf(v);
}

// ---------------- decoder: LDS-free MFMA GEMM, B from fragment-packed emb
constexpr int DEC_BM = 64, DEC_BN = 256;
constexpr int DEC_GX = B / DEC_BM;          // 16
constexpr int DEC_GY = VPAD / DEC_BN;       // 196
constexpr int DEC_NWG = DEC_GX * DEC_GY;    // 3136 (div by 8)

__global__ __launch_bounds__(256) void k_dec2(const unsigned short* __restrict__ obj_bf,
                                              const unsigned short* __restrict__ emb_pk,
                                              const float* __restrict__ ent_bias,
                                              float* __restrict__ score) {
    int t = threadIdx.x;
    int lane = t & 63, wid = t >> 6;
    int wg = (blockIdx.x & 7) * (DEC_NWG >> 3) + (blockIdx.x >> 3);
    int b0 = (wg & (DEC_GX - 1)) * DEC_BM;
    int v0 = (wg >> 4) * DEC_BN;
    int r16 = lane & 15;
    int kc = (lane >> 4) * 8;
    int vbase = v0 + wid * 64;
    int vtbase = vbase >> 4;
    const unsigned short* gA = obj_bf + (size_t)(b0 + r16) * K2 + kc;
    f32x4 acc[4][4] = {};
    for (int ks = 0; ks < 7; ++ks) {
        int kof = ks * 32;
        bf16x8 a[4], bb[4];
#pragma unroll
        for (int mf = 0; mf < 4; ++mf)
            a[mf] = *(const bf16x8*)(gA + (size_t)(mf * 16) * K2 + kof);
#pragma unroll
        for (int nf = 0; nf < 4; ++nf)
            bb[nf] = *(const bf16x8*)&emb_pk[(((size_t)(vtbase + nf) * 7 + ks) * 64 + lane) * 8];
#pragma unroll
        for (int mf = 0; mf < 4; ++mf)
#pragma unroll
            for (int nf = 0; nf < 4; ++nf)
                acc[mf][nf] = __builtin_amdgcn_mfma_f32_16x16x32_bf16(a[mf], bb[nf],
                                                                      acc[mf][nf], 0, 0, 0);
    }
#pragma unroll
    for (int nf = 0; nf < 4; ++nf) {
        int v = vbase + nf * 16 + r16;
        if (v >= V) continue;
        float bias = ent_bias[v];
#pragma unroll
        for (int mf = 0; mf < 4; ++mf) {
            int brow = b0 + mf * 16 + (lane >> 4) * 4;
            f32x4 av = acc[mf][nf];
#pragma unroll
            for (int i = 0; i < 4; ++i) {
                float val = av[i] + bias;
                score[(size_t)(brow + i) * V + v] = 1.f / (1.f + __expf(-val));
            }
        }
    }
}

extern "C" void kernel_launch(void* const* d_in, const int* in_sizes, int n_in,
                              void* d_out, int out_size, void* d_ws, size_t ws_size,
                              hipStream_t stream) {
    const int*   edge_src  = (const int*)d_in[0];
    const int*   edge_dst  = (const int*)d_in[1];
    const int*   edge_type = (const int*)d_in[2];
    const int*   head      = (const int*)d_in[3];
    const int*   rela      = (const int*)d_in[4];
    const float* edge_norm = (const float*)d_in[5];
    const float* ent_emb   = (const float*)d_in[6];
    const float* rel_emb   = (const float*)d_in[7];
    const float* in_w      = (const float*)d_in[8];
    const float* out_w     = (const float*)d_in[9];
    const float* loop_w    = (const float*)d_in[10];
    const float* w_rel     = (const float*)d_in[11];
    const float* loop_rel  = (const float*)d_in[12];
    const float* conv_bias = (const float*)d_in[13];
    const float* bn_gamma  = (const float*)d_in[14];
    const float* bn_beta   = (const float*)d_in[15];
    const float* emb_ent   = (const float*)d_in[16];
    const float* ent_bias  = (const float*)d_in[17];
    float* score = (float*)d_out;

    // ---- workspace layout
    char* w = (char*)d_ws;
    float*          agg    = (float*)w;                      w += (size_t)V * OUT * 4;   // 40 MB
    unsigned short* Mtab   = (unsigned short*)w;             w += (size_t)NKEY * MT_SZ * 2;  // 42.6 MB
    unsigned*       perm1  = (unsigned*)w;                   w += (size_t)E1MAX * 4;
    int*            poslist  = (int*)w;                      w += (size_t)E * 4;
    uint2*          pairs    = (uint2*)w;                    w += (size_t)NB2 * BCAP * 8;
    char* zbase = w;
    int*   hist1     = (int*)w;                              w += NKEY * 4;
    int*   cursor1   = (int*)w;                              w += NKEY * 4;
    int*   cursor196 = (int*)w;                              w += NB2 * 4;
    float* colsum    = (float*)w;                            w += OUT * 4;
    float* colsq     = (float*)w;                            w += OUT * 4;
    size_t zbytes = (size_t)(w - zbase);
    int*   start1  = (int*)w;                                w += (NKEY + 1) * 4;
    int*   start2  = (int*)w;                                w += (V + 4) * 4;
    int*   Edev    = (int*)w;                                w += 16;
    float* Mloop   = (float*)w;                              w += (size_t)D * OUT * 4;
    float* r_out   = (float*)w;                              w += (size_t)R * OUT * 4;
    unsigned short* obj_bf = (unsigned short*)w;             w += (size_t)B * K2 * 2;
    unsigned short* WT_bf  = (unsigned short*)w;             w += (size_t)2 * 208 * 128 * 2;
    // overlays (strictly stream-ordered):
    unsigned short* ent_bf = (unsigned short*)agg;   // V*128 ushorts; dead after k_edgemm
    unsigned short* emb_pk = (unsigned short*)Mtab;  // NTILE*448*8 ushorts (22.5 MB); Mtab dead after k_edgemm
    unsigned short* msg    = (unsigned short*)d_out; // E1MAX*200 ushorts; dead after k_aggx

    (void)hipMemsetAsync(zbase, 0, zbytes, stream);

    k_pre<<<PRE_NWG, 256, 0, stream>>>(loop_rel, loop_w, rel_emb, w_rel, in_w, out_w,
                                       ent_emb, edge_type, Mloop, r_out, WT_bf, ent_bf,
                                       hist1);
    k_scan<<<1, 1024, 0, stream>>>(hist1, start1, Edev, perm1);
    k_bin<<<(E + 8191) / 8192, 1024, 0, stream>>>(edge_type, edge_dst, start1,
                                                  cursor1, cursor196, perm1, pairs);
    k_bd2mt<<<BD2MT_NWG, 256, 0, stream>>>(cursor196, pairs, rel_emb, WT_bf,
                                           start2, poslist, Mtab);
    k_edgemm<<<E1MAX / 64 / ECHK, 256, 0, stream>>>(perm1, Edev, edge_src, edge_norm,
                                                    ent_bf, Mtab, msg);
    k_aggx<<<V / 16, 256, 0, stream>>>(start2, poslist, msg, ent_emb, Mloop,
                                       conv_bias, agg);
    k_stcv<<<STCV_NWG, 256, 0, stream>>>(agg, emb_ent, colsum, colsq, emb_pk);
    k_obj<<<B, 256, 0, stream>>>(head, rela, agg, colsum, colsq, bn_gamma, bn_beta,
                                 r_out, obj_bf);
    k_dec2<<<DEC_NWG, 256, 0, stream>>>(obj_bf, emb_pk, ent_bias, score);
}

// Round 15
// 399.376 us; speedup vs baseline: 1.0274x; 1.0274x over previous
//
#include <hip/hip_runtime.h>
#include <cstddef>

constexpr int V = 50000, E = 400000, R = 400, D = 100, OUT = 200, B = 1024;
constexpr int HALF = E / 2;
constexpr float EPS = 1e-5f;
constexpr int K2 = 232;        // obj K pad (bf16)
constexpr int VPAD = 50176;    // 196*256
constexpr int NTILE = VPAD / 16;  // 3136 v-tiles for packed emb
constexpr int NKEY = 800;      // (rel, side)
constexpr int E1MAX = 450560;  // E + NKEY*63 rounded up; /64 = 7040 chunks
constexpr int MT_O = 208, MT_K = 128;
constexpr int MT_SZ = MT_O * MT_K;
constexpr int NB2 = 196;       // coarse dst buckets (dst>>8)
constexpr int BCAP = 2560;     // bucket capacity
constexpr int ECHK = 8;        // chunks per edgemm block; 7040/8=880 (div 8)
constexpr int BIN_EPB = 2048;  // edges per k_bin block
constexpr int BIN_THREADS = 512;

typedef short bf16x8 __attribute__((ext_vector_type(8)));
typedef float f32x4  __attribute__((ext_vector_type(4)));
typedef unsigned short ushort8 __attribute__((ext_vector_type(8)));
typedef __attribute__((address_space(1))) const unsigned int guint_t;
typedef __attribute__((address_space(3))) unsigned int luint_t;

__device__ inline unsigned short f2bf(float x) {
    unsigned u = __float_as_uint(x);
    u = (u + 0x7fffu + ((u >> 16) & 1u)) >> 16;
    return (unsigned short)u;
}
__device__ inline float bf2f(unsigned short u) {
    return __uint_as_float(((unsigned)u) << 16);
}

// ---------------- fused precompute + key-hist: Mloop | r_out | WT_bf | ent_bf | hist1
constexpr int G_MLOOP = (D * OUT + 255) / 256;       // 79
constexpr int G_ROUT  = (R * OUT + 255) / 256;       // 313
constexpr int G_CVTWT = (2 * 208 * 16) / 256;        // 26
constexpr int G_CVTENT = (V * 16) / 256;             // 3125
constexpr int G_HIST = 512;
constexpr int PRE_B1 = G_MLOOP;
constexpr int PRE_B2 = PRE_B1 + G_ROUT;
constexpr int PRE_B3 = PRE_B2 + G_CVTWT;
constexpr int PRE_B4 = PRE_B3 + G_CVTENT;
constexpr int PRE_NWG = PRE_B4 + G_HIST;

__global__ __launch_bounds__(256) void k_pre(const float* __restrict__ loop_rel,
                                             const float* __restrict__ loop_w,
                                             const float* __restrict__ rel_emb,
                                             const float* __restrict__ w_rel,
                                             const float* __restrict__ in_w,
                                             const float* __restrict__ out_w,
                                             const float* __restrict__ ent_emb,
                                             const int* __restrict__ etyp,
                                             float* __restrict__ Mloop,
                                             float* __restrict__ r_out,
                                             unsigned short* __restrict__ WT_bf,
                                             unsigned short* __restrict__ ent_bf,
                                             int* __restrict__ hist1) {
    __shared__ int lh[NKEY];
    int blk = blockIdx.x, t = threadIdx.x;
    if (blk < PRE_B1) {
        int i = blk * 256 + t;
        if (i >= D * OUT) return;
        int j = i / OUT, o = i % OUT;
        float s = 0.f;
        for (int k = 0; k < D; ++k) {
            int idx = j + k; if (idx >= D) idx -= D;
            s += loop_rel[idx] * loop_w[k * OUT + o];
        }
        Mloop[i] = s;
    } else if (blk < PRE_B2) {
        int i = (blk - PRE_B1) * 256 + t;
        if (i >= R * OUT) return;
        int r = i / OUT, o = i % OUT;
        float s = 0.f;
        for (int k = 0; k < D; ++k) s += rel_emb[r * D + k] * w_rel[k * OUT + o];
        r_out[i] = s;
    } else if (blk < PRE_B3) {
        int i = (blk - PRE_B2) * 256 + t;
        int side = i / (208 * 16);
        int rem = i - side * 208 * 16;
        int o = rem >> 4, c8 = rem & 15;
        int k0 = c8 * 8;
        const float* __restrict__ W = side ? out_w : in_w;
        ushort8 v = (ushort8)0;
        if (o < 200) {
#pragma unroll
            for (int q = 0; q < 8; ++q) {
                int k = k0 + q;
                if (k < 100) v[q] = f2bf(W[k * OUT + o]);
            }
        }
        *(ushort8*)&WT_bf[((size_t)side * 208 + o) * 128 + k0] = v;
    } else if (blk < PRE_B4) {
        int i = (blk - PRE_B3) * 256 + t;
        if (i >= V * 16) return;
        int v = i >> 4, c8 = i & 15;
        int c0 = c8 * 8;
        ushort8 o = (ushort8)0;
        if (c0 < 96) {
            float4 f0 = *(const float4*)&ent_emb[(size_t)v * D + c0];
            float4 f1 = *(const float4*)&ent_emb[(size_t)v * D + c0 + 4];
            o[0] = f2bf(f0.x); o[1] = f2bf(f0.y); o[2] = f2bf(f0.z); o[3] = f2bf(f0.w);
            o[4] = f2bf(f1.x); o[5] = f2bf(f1.y); o[6] = f2bf(f1.z); o[7] = f2bf(f1.w);
        } else if (c0 == 96) {
            float4 f0 = *(const float4*)&ent_emb[(size_t)v * D + 96];
            o[0] = f2bf(f0.x); o[1] = f2bf(f0.y); o[2] = f2bf(f0.z); o[3] = f2bf(f0.w);
        }
        *(ushort8*)&ent_bf[(size_t)v * 128 + c0] = o;
    } else {                                  // key histogram (LDS-aggregated)
        int hb = blk - PRE_B4;
        for (int i = t; i < NKEY; i += 256) lh[i] = 0;
        __syncthreads();
        for (int e = hb * 256 + t; e < E; e += G_HIST * 256) {
            int key = etyp[e] + (e < HALF ? 0 : R);
            atomicAdd(&lh[key], 1);
        }
        __syncthreads();
        for (int i = t; i < NKEY; i += 256) {
            int c = lh[i];
            if (c) atomicAdd(&hist1[i], c);
        }
    }
}

// ---------------- key scan (64-aligned buckets) + perm1 pad-tail fill
__global__ __launch_bounds__(1024) void k_scan(const int* __restrict__ hist1,
                                               int* __restrict__ start1,
                                               int* __restrict__ Edev,
                                               unsigned* __restrict__ perm1) {
    __shared__ int buf[1024];
    int t = threadIdx.x;
    int h = (t < NKEY) ? hist1[t] : 0;
    int c = (h + 63) & ~63;
    buf[t] = c; __syncthreads();
    for (int off = 1; off < 1024; off <<= 1) {
        int x = (t >= off) ? buf[t - off] : 0; __syncthreads();
        buf[t] += x; __syncthreads();
    }
    int s = buf[t] - c;
    if (t < NKEY) {
        start1[t] = s;
        for (int i = h; i < c; ++i) perm1[s + i] = 0xFFFFFFFFu;  // sentinel pad tail
    }
    if (t == NKEY - 1) { start1[NKEY] = buf[t]; *Edev = buf[t]; }
}

// ---------------- fused binning: perm1 scatter + dst pairs in ONE pass
__global__ __launch_bounds__(BIN_THREADS) void k_bin(const int* __restrict__ etyp,
                                                     const int* __restrict__ edst,
                                                     const int* __restrict__ start1,
                                                     int* __restrict__ cursor1,
                                                     int* __restrict__ cursor196,
                                                     unsigned* __restrict__ perm1,
                                                     uint2* __restrict__ pairs) {
    __shared__ int lhist[NKEY], lbase[NKEY], lcnt[NKEY];
    __shared__ int chist[NB2], cbase[NB2], ccnt[NB2];
    int t = threadIdx.x;
    int e0 = blockIdx.x * BIN_EPB;
    for (int i = t; i < NKEY; i += BIN_THREADS) { lhist[i] = 0; lcnt[i] = 0; }
    for (int i = t; i < NB2; i += BIN_THREADS) { chist[i] = 0; ccnt[i] = 0; }
    __syncthreads();
    for (int i = t; i < BIN_EPB; i += BIN_THREADS) {
        int e = e0 + i;
        if (e < E) {
            int key = etyp[e] + (e < HALF ? 0 : R);
            atomicAdd(&lhist[key], 1);
            atomicAdd(&chist[edst[e] >> 8], 1);
        }
    }
    __syncthreads();
    for (int i = t; i < NKEY; i += BIN_THREADS) {
        int c = lhist[i];
        lbase[i] = c ? (start1[i] + atomicAdd(&cursor1[i], c)) : 0;
    }
    for (int i = t; i < NB2; i += BIN_THREADS) {
        int c = chist[i];
        cbase[i] = c ? atomicAdd(&cursor196[i], c) : 0;
    }
    __syncthreads();
    for (int i = t; i < BIN_EPB; i += BIN_THREADS) {
        int e = e0 + i;
        if (e < E) {
            int key = etyp[e] + (e < HALF ? 0 : R);
            int r = atomicAdd(&lcnt[key], 1);
            int p = lbase[key] + r;
            perm1[p] = (unsigned)e | ((unsigned)key << 19);
            int d = edst[e];
            int ld = d >> 8;
            int rr = atomicAdd(&ccnt[ld], 1);
            int slot = cbase[ld] + rr;
            if (slot < BCAP)
                pairs[(size_t)ld * BCAP + slot] = make_uint2((unsigned)d, (unsigned)p);
        }
    }
}

// ---------------- fused: per-bucket dst ranking | Mt table build (MFMA)
constexpr int BD2MT_NWG = NB2 + NKEY;   // 196 + 800

__global__ __launch_bounds__(256) void k_bd2mt(const int* __restrict__ cursor196,
                                               const uint2* __restrict__ pairs,
                                               const float* __restrict__ rel_emb,
                                               const unsigned short* __restrict__ WT_bf,
                                               int* __restrict__ start2,
                                               int* __restrict__ poslist,
                                               unsigned short* __restrict__ Mtab) {
    int blk = blockIdx.x, t = threadIdx.x;
    if (blk < NB2) {   // ---- dst ranking
        __shared__ int lcnt[256], loff[256], lrk[256], bscan[256];
        int b = blk;
        lcnt[t] = 0; lrk[t] = 0;
        bscan[t] = (t < NB2) ? min(cursor196[t], BCAP) : 0;
        __syncthreads();
        for (int off = 1; off < 256; off <<= 1) {
            int xx = (t >= off) ? bscan[t - off] : 0; __syncthreads();
            bscan[t] += xx; __syncthreads();
        }
        int base = (b > 0) ? bscan[b - 1] : 0;
        if (b == 0 && t == 0) start2[V] = bscan[NB2 - 1];
        int n = min(cursor196[b], BCAP);
        for (int i = t; i < n; i += 256) {
            int d = (int)pairs[(size_t)b * BCAP + i].x;
            atomicAdd(&lcnt[d - (b << 8)], 1);
        }
        __syncthreads();
        int cc = lcnt[t];
        loff[t] = cc; __syncthreads();
        for (int off = 1; off < 256; off <<= 1) {
            int xx = (t >= off) ? loff[t - off] : 0; __syncthreads();
            loff[t] += xx; __syncthreads();
        }
        int excl = loff[t] - cc;
        loff[t] = excl;
        int d = (b << 8) + t;
        if (d < V) start2[d] = base + excl;
        __syncthreads();
        for (int i = t; i < n; i += 256) {
            uint2 pr = pairs[(size_t)b * BCAP + i];
            int ld = (int)pr.x - (b << 8);
            int r = atomicAdd(&lrk[ld], 1);
            poslist[base + loff[ld] + r] = (int)pr.y;
        }
    } else {           // ---- Mt[key] = WT_bf[side] @ Hankel(r) via MFMA
        __shared__ unsigned short rsh[256];
        int key = blk - NB2;
        int rho = (key < R) ? key : key - R;
        int side = (key < R) ? 0 : 1;
        int lane = t & 63, wid = t >> 6;
        {
            int sm = t;
            if (sm >= 200) sm -= 200; else if (sm >= 100) sm -= 100;
            rsh[t] = f2bf(rel_emb[rho * D + sm]);
        }
        __syncthreads();
        const unsigned short* WT = WT_bf + (size_t)side * 208 * 128;
        unsigned short* MtK = Mtab + (size_t)key * MT_SZ;
        int m16 = lane & 15, kq = lane >> 4;
        for (int jt = 0; jt < 2; ++jt) {
            int j0 = (wid * 2 + jt) * 16;
            f32x4 acc[13] = {};
            for (int ks = 0; ks < 4; ++ks) {
                int rbase = ks * 32 + kq * 8 + j0 + m16;   // max 254
                ushort8 tmp;
#pragma unroll
                for (int q = 0; q < 8; ++q) tmp[q] = rsh[rbase + q];
                bf16x8 bfr = *(bf16x8*)&tmp;
#pragma unroll
                for (int of = 0; of < 13; ++of) {
                    bf16x8 afr = *(const bf16x8*)&WT[(size_t)(of * 16 + m16) * 128 + ks * 32 + kq * 8];
                    acc[of] = __builtin_amdgcn_mfma_f32_16x16x32_bf16(afr, bfr, acc[of], 0, 0, 0);
                }
            }
#pragma unroll
            for (int of = 0; of < 13; ++of) {
                int orow = of * 16 + kq * 4;
#pragma unroll
                for (int q = 0; q < 4; ++q)
                    MtK[(size_t)(orow + q) * MT_K + j0 + m16] = f2bf(acc[of][q]);
            }
        }
    }
}

// ---------------- per-chunk MFMA with Mt reuse across 8 chunks per block
__global__ __launch_bounds__(256, 2) void k_edgemm(const unsigned* __restrict__ perm1,
                                                   const int* __restrict__ Edev,
                                                   const int* __restrict__ esrc,
                                                   const float* __restrict__ enorm,
                                                   const unsigned short* __restrict__ ent_bf,
                                                   const unsigned short* __restrict__ Mtab,
                                                   unsigned short* __restrict__ msg) {
    __shared__ __align__(16) unsigned short MtL[MT_SZ];      // 53,248 B
    __shared__ __align__(16) unsigned short AtL[64 * MT_K];  // 16,384 B
    __shared__ float snrm[2][64];
    __shared__ int ssrc[2][64];
    int t = threadIdx.x, lane = t & 63, wid = t >> 6;
    int cpx = gridDim.x >> 3;
    int blk = (blockIdx.x & 7) * cpx + (blockIdx.x >> 3);
    int nE = *Edev;
    int curkey = -1;
    for (int c = 0; c < ECHK; ++c) {
        int chunk = blk * ECHK + c;
        if (chunk * 64 >= nE) break;
        int buf = c & 1;
        if (t < 64) {
            unsigned val = perm1[chunk * 64 + t];
            int e = (int)(val & 0x7FFFFu);
            bool ok = (val != 0xFFFFFFFFu);
            ssrc[buf][t] = ok ? esrc[e] : 0;
            snrm[buf][t] = ok ? enorm[e] : 0.f;
        }
        int key = (int)(perm1[chunk * 64] >> 19);   // chunk base is always real
        __syncthreads();
        if (key != curkey) {
            for (int i = 0; i < 13; ++i) {
                int G0 = (wid * 13 + i) * 64;
                int G = G0 + lane;
                int o = G >> 4, g = G & 15;
                int gs = g ^ (o & 7);
                __builtin_amdgcn_global_load_lds(
                    (guint_t*)(Mtab + (size_t)key * MT_SZ + o * MT_K + gs * 8),
                    (luint_t*)(MtL + (size_t)G0 * 8), 16, 0, 0);
            }
            curkey = key;
        }
        for (int i = 0; i < 4; ++i) {
            int base = (wid * 4 + i) * 1024;
            int Gb = base + lane * 16;
            int row = Gb >> 8;
            int g = (Gb >> 4) & 15;
            int gs = g ^ (row & 7);
            __builtin_amdgcn_global_load_lds(
                (guint_t*)(ent_bf + (size_t)ssrc[buf][row] * 128 + gs * 8),
                (luint_t*)((char*)AtL + base), 16, 0, 0);
        }
        __syncthreads();
        int erow = wid * 16 + (lane & 15);
        int kq = lane >> 4;
        f32x4 acc[13] = {};
        for (int ks = 0; ks < 4; ++ks) {
            int g = ks * 4 + kq;
            bf16x8 bfr = *(const bf16x8*)((const char*)AtL + erow * 256 + ((g ^ (erow & 7)) * 16));
#pragma unroll
            for (int of = 0; of < 13; ++of) {
                int orow = of * 16 + (lane & 15);
                bf16x8 afr = *(const bf16x8*)((const char*)MtL + orow * 256 + ((g ^ (orow & 7)) * 16));
                acc[of] = __builtin_amdgcn_mfma_f32_16x16x32_bf16(afr, bfr, acc[of], 0, 0, 0);
            }
        }
        float nr = snrm[buf][erow];
        size_t rowbase = (size_t)(chunk * 64 + erow) * OUT;
#pragma unroll
        for (int of = 0; of < 13; ++of) {
            int o0 = of * 16 + kq * 4;
            if (o0 < OUT) {
                ushort4 pk;
                pk.x = f2bf(acc[of][0] * nr); pk.y = f2bf(acc[of][1] * nr);
                pk.z = f2bf(acc[of][2] * nr); pk.w = f2bf(acc[of][3] * nr);
                *(ushort4*)&msg[rowbase + o0] = pk;
            }
        }
    }
}

// ---------------- fused gather-sum + loop-term + bias
__global__ __launch_bounds__(256) void k_aggx(const int* __restrict__ start2,
                                              const int* __restrict__ poslist,
                                              const unsigned short* __restrict__ msg,
                                              const float* __restrict__ ent_emb,
                                              const float* __restrict__ Mloop,
                                              const float* __restrict__ conv_bias,
                                              float* __restrict__ x) {
    __shared__ float xt[16][200];
    __shared__ float sat[100][20];
    int t = threadIdx.x, lane = t & 63, wid = t >> 6;
    int v0 = blockIdx.x * 16;
    int half = (lane >= 25 && lane < 50) ? 1 : 0;
    int c = lane - half * 25;
    bool act = lane < 50;
    int src = lane + 25 < 64 ? lane + 25 : 63;
    for (int i = 0; i < 4; ++i) {
        int v = v0 + wid * 4 + i;
        int s = start2[v], epos = start2[v + 1];
        float acc[8] = {};
        for (int q = s; q < epos; q += 2) {
            int qq = q + half;
            if (act && qq < epos) {
                int p = poslist[qq];
                ushort8 m = *(const ushort8*)&msg[(size_t)p * OUT + c * 8];
#pragma unroll
                for (int j = 0; j < 8; ++j) acc[j] += bf2f(m[j]);
            }
        }
#pragma unroll
        for (int j = 0; j < 8; ++j) {
            float o = __shfl(acc[j], src);
            if (lane < 25) acc[j] += o;
        }
        if (lane < 25) {
#pragma unroll
            for (int j = 0; j < 8; ++j) xt[wid * 4 + i][lane * 8 + j] = acc[j];
        }
    }
    for (int i = t; i < 400; i += 256) {
        int kg = i >> 4, vv = i & 15;
        float4 a4 = *(const float4*)&ent_emb[(size_t)(v0 + vv) * D + kg * 4];
        sat[kg * 4 + 0][vv] = a4.x;
        sat[kg * 4 + 1][vv] = a4.y;
        sat[kg * 4 + 2][vv] = a4.z;
        sat[kg * 4 + 3][vv] = a4.w;
    }
    __syncthreads();
    if (t < 200) {
        int og = t % 50, eg = t / 50;
        int o0 = og * 4, vv0 = eg * 4;
        float acc[4][4] = {};
        for (int k = 0; k < D; ++k) {
            float4 w4 = *(const float4*)&Mloop[k * OUT + o0];
            float4 ca = *(const float4*)&sat[k][vv0];
            float cc[4] = {ca.x, ca.y, ca.z, ca.w};
            float wv[4] = {w4.x, w4.y, w4.z, w4.w};
#pragma unroll
            for (int r = 0; r < 4; ++r)
#pragma unroll
                for (int j = 0; j < 4; ++j) acc[r][j] += cc[r] * wv[j];
        }
        float4 bi = *(const float4*)&conv_bias[o0];
        float bv[4] = {bi.x, bi.y, bi.z, bi.w};
#pragma unroll
        for (int r = 0; r < 4; ++r) {
            int vv = vv0 + r;
            float4 ov;
            ov.x = (xt[vv][o0 + 0] + acc[r][0]) * (1.f / 3.f) + bv[0];
            ov.y = (xt[vv][o0 + 1] + acc[r][1]) * (1.f / 3.f) + bv[1];
            ov.z = (xt[vv][o0 + 2] + acc[r][2]) * (1.f / 3.f) + bv[2];
            ov.w = (xt[vv][o0 + 3] + acc[r][3]) * (1.f / 3.f) + bv[3];
            *(float4*)&x[(size_t)(v0 + vv) * OUT + o0] = ov;
        }
    }
}

// ---------------- fused: BN stats | emb fragment-packed conversion
constexpr int G_STATS = 400;
constexpr int G_PKEMB = (NTILE * 448) / 256;    // 5488
constexpr int STCV_NWG = G_STATS + G_PKEMB;

__global__ __launch_bounds__(256) void k_stcv(const float* __restrict__ x,
                                              const float* __restrict__ emb_ent,
                                              float* __restrict__ colsum,
                                              float* __restrict__ colsq,
                                              unsigned short* __restrict__ emb_pk) {
    int blk = blockIdx.x, t = threadIdx.x;
    if (blk < G_STATS) {
        int g = blk * 256 + t;
        int col = g % OUT;
        int r0 = g / OUT;
        float s = 0.f, sq = 0.f;
        for (int r = r0; r < V; r += 512) {
            float v = x[(size_t)r * OUT + col];
            s += v;
            sq += v * v;
        }
        atomicAdd(&colsum[col], s);
        atomicAdd(&colsq[col], sq);
    } else {
        int i = (blk - G_STATS) * 256 + t;
        if (i >= NTILE * 448) return;
        int vt = i / 448, r = i - vt * 448;
        int lane = r & 63;
        int ks = r >> 6;
        int v = vt * 16 + (lane & 15);
        int k0 = ks * 32 + (lane >> 4) * 8;
        ushort8 o = (ushort8)0;
        if (v < V && k0 < 200) {
            float4 f0 = *(const float4*)&emb_ent[(size_t)v * OUT + k0];
            float4 f1 = *(const float4*)&emb_ent[(size_t)v * OUT + k0 + 4];
            o[0] = f2bf(f0.x); o[1] = f2bf(f0.y); o[2] = f2bf(f0.z); o[3] = f2bf(f0.w);
            o[4] = f2bf(f1.x); o[5] = f2bf(f1.y); o[6] = f2bf(f1.z); o[7] = f2bf(f1.w);
        }
        *(ushort8*)&emb_pk[(size_t)i * 8] = o;
    }
}

// ---------------- obj_bf (inline mean/rstd)
__global__ __launch_bounds__(256) void k_obj(const int* __restrict__ head,
                                             const int* __restrict__ rela,
                                             const float* __restrict__ x,
                                             const float* __restrict__ colsum,
                                             const float* __restrict__ colsq,
                                             const float* __restrict__ gamma,
                                             const float* __restrict__ beta,
                                             const float* __restrict__ r_out,
                                             unsigned short* __restrict__ obj_bf) {
    int b = blockIdx.x, t = threadIdx.x;
    if (t >= K2) return;
    float v = 0.f;
    if (t < OUT) {
        float m = colsum[t] / (float)V;
        float var = colsq[t] / (float)V - m * m;
        float rs = rsqrtf(var + EPS);
        int h = head[b], r = rela[b];
        float val = (x[(size_t)h * OUT + t] - m) * rs * gamma[t] + beta[t];
        val = tanhf(val);
        v = val * r_out[r * OUT + t];
    }
    obj_bf[(size_t)b * K2 + t] = f2bf(v);
}

// ---------------- decoder: LDS-free MFMA GEMM, B from fragment-packed emb
constexpr int DEC_BM = 64, DEC_BN = 256;
constexpr int DEC_GX = B / DEC_BM;          // 16
constexpr int DEC_GY = VPAD / DEC_BN;       // 196
constexpr int DEC_NWG = DEC_GX * DEC_GY;    // 3136 (div by 8)

__global__ __launch_bounds__(256) void k_dec2(const unsigned short* __restrict__ obj_bf,
                                              const unsigned short* __restrict__ emb_pk,
                                              const float* __restrict__ ent_bias,
                                              float* __restrict__ score) {
    int t = threadIdx.x;
    int lane = t & 63, wid = t >> 6;
    int wg = (blockIdx.x & 7) * (DEC_NWG >> 3) + (blockIdx.x >> 3);
    int b0 = (wg & (DEC_GX - 1)) * DEC_BM;
    int v0 = (wg >> 4) * DEC_BN;
    int r16 = lane & 15;
    int kc = (lane >> 4) * 8;
    int vbase = v0 + wid * 64;
    int vtbase = vbase >> 4;
    const unsigned short* gA = obj_bf + (size_t)(b0 + r16) * K2 + kc;
    f32x4 acc[4][4] = {};
    for (int ks = 0; ks < 7; ++ks) {
        int kof = ks * 32;
        bf16x8 a[4], bb[4];
#pragma unroll
        for (int mf = 0; mf < 4; ++mf)
            a[mf] = *(const bf16x8*)(gA + (size_t)(mf * 16) * K2 + kof);
#pragma unroll
        for (int nf = 0; nf < 4; ++nf)
            bb[nf] = *(const bf16x8*)&emb_pk[(((size_t)(vtbase + nf) * 7 + ks) * 64 + lane) * 8];
#pragma unroll
        for (int mf = 0; mf < 4; ++mf)
#pragma unroll
            for (int nf = 0; nf < 4; ++nf)
                acc[mf][nf] = __builtin_amdgcn_mfma_f32_16x16x32_bf16(a[mf], bb[nf],
                                                                      acc[mf][nf], 0, 0, 0);
    }
#pragma unroll
    for (int nf = 0; nf < 4; ++nf) {
        int v = vbase + nf * 16 + r16;
        if (v >= V) continue;
        float bias = ent_bias[v];
#pragma unroll
        for (int mf = 0; mf < 4; ++mf) {
            int brow = b0 + mf * 16 + (lane >> 4) * 4;
            f32x4 av = acc[mf][nf];
#pragma unroll
            for (int i = 0; i < 4; ++i) {
                float val = av[i] + bias;
                score[(size_t)(brow + i) * V + v] = 1.f / (1.f + __expf(-val));
            }
        }
    }
}

extern "C" void kernel_launch(void* const* d_in, const int* in_sizes, int n_in,
                              void* d_out, int out_size, void* d_ws, size_t ws_size,
                              hipStream_t stream) {
    const int*   edge_src  = (const int*)d_in[0];
    const int*   edge_dst  = (const int*)d_in[1];
    const int*   edge_type = (const int*)d_in[2];
    const int*   head      = (const int*)d_in[3];
    const int*   rela      = (const int*)d_in[4];
    const float* edge_norm = (const float*)d_in[5];
    const float* ent_emb   = (const float*)d_in[6];
    const float* rel_emb   = (const float*)d_in[7];
    const float* in_w      = (const float*)d_in[8];
    const float* out_w     = (const float*)d_in[9];
    const float* loop_w    = (const float*)d_in[10];
    const float* w_rel     = (const float*)d_in[11];
    const float* loop_rel  = (const float*)d_in[12];
    const float* conv_bias = (const float*)d_in[13];
    const float* bn_gamma  = (const float*)d_in[14];
    const float* bn_beta   = (const float*)d_in[15];
    const float* emb_ent   = (const float*)d_in[16];
    const float* ent_bias  = (const float*)d_in[17];
    float* score = (float*)d_out;

    // ---- workspace layout
    char* w = (char*)d_ws;
    float*          agg    = (float*)w;                      w += (size_t)V * OUT * 4;   // 40 MB
    unsigned short* Mtab   = (unsigned short*)w;             w += (size_t)NKEY * MT_SZ * 2;  // 42.6 MB
    unsigned*       perm1  = (unsigned*)w;                   w += (size_t)E1MAX * 4;
    int*            poslist  = (int*)w;                      w += (size_t)E * 4;
    uint2*          pairs    = (uint2*)w;                    w += (size_t)NB2 * BCAP * 8;
    char* zbase = w;
    int*   hist1     = (int*)w;                              w += NKEY * 4;
    int*   cursor1   = (int*)w;                              w += NKEY * 4;
    int*   cursor196 = (int*)w;                              w += NB2 * 4;
    float* colsum    = (float*)w;                            w += OUT * 4;
    float* colsq     = (float*)w;                            w += OUT * 4;
    size_t zbytes = (size_t)(w - zbase);
    int*   start1  = (int*)w;                                w += (NKEY + 1) * 4;
    int*   start2  = (int*)w;                                w += (V + 4) * 4;
    int*   Edev    = (int*)w;                                w += 16;
    float* Mloop   = (float*)w;                              w += (size_t)D * OUT * 4;
    float* r_out   = (float*)w;                              w += (size_t)R * OUT * 4;
    unsigned short* obj_bf = (unsigned short*)w;             w += (size_t)B * K2 * 2;
    unsigned short* WT_bf  = (unsigned short*)w;             w += (size_t)2 * 208 * 128 * 2;
    // overlays (strictly stream-ordered):
    unsigned short* ent_bf = (unsigned short*)agg;   // V*128 ushorts; dead after k_edgemm
    unsigned short* emb_pk = (unsigned short*)Mtab;  // NTILE*448*8 ushorts; Mtab dead after k_edgemm
    unsigned short* msg    = (unsigned short*)d_out; // E1MAX*200 ushorts; dead after k_aggx

    (void)hipMemsetAsync(zbase, 0, zbytes, stream);

    k_pre<<<PRE_NWG, 256, 0, stream>>>(loop_rel, loop_w, rel_emb, w_rel, in_w, out_w,
                                       ent_emb, edge_type, Mloop, r_out, WT_bf, ent_bf,
                                       hist1);
    k_scan<<<1, 1024, 0, stream>>>(hist1, start1, Edev, perm1);
    k_bin<<<(E + BIN_EPB - 1) / BIN_EPB, BIN_THREADS, 0, stream>>>(
        edge_type, edge_dst, start1, cursor1, cursor196, perm1, pairs);
    k_bd2mt<<<BD2MT_NWG, 256, 0, stream>>>(cursor196, pairs, rel_emb, WT_bf,
                                           start2, poslist, Mtab);
    k_edgemm<<<E1MAX / 64 / ECHK, 256, 0, stream>>>(perm1, Edev, edge_src, edge_norm,
                                                    ent_bf, Mtab, msg);
    k_aggx<<<V / 16, 256, 0, stream>>>(start2, poslist, msg, ent_emb, Mloop,
                                       conv_bias, agg);
    k_stcv<<<STCV_NWG, 256, 0, stream>>>(agg, emb_ent, colsum, colsq, emb_pk);
    k_obj<<<B, 256, 0, stream>>>(head, rela, agg, colsum, colsq, bn_gamma, bn_beta,
                                 r_out, obj_bf);
    k_dec2<<<DEC_NWG, 256, 0, stream>>>(obj_bf, emb_pk, ent_bias, score);
}

// Round 16
// 388.939 us; speedup vs baseline: 1.0550x; 1.0268x over previous
//
#include <hip/hip_runtime.h>
#include <cstddef>

constexpr int V = 50000, E = 400000, R = 400, D = 100, OUT = 200, B = 1024;
constexpr int HALF = E / 2;
constexpr float EPS = 1e-5f;
constexpr int K2 = 232;        // obj K pad (bf16)
constexpr int VPAD = 50176;    // 196*256
constexpr int NTILE = VPAD / 16;  // 3136 v-tiles for packed emb
constexpr int NKEY = 800;      // (rel, side)
constexpr int E1MAX = 450560;  // E + NKEY*63 rounded up; /64 = 7040 chunks
constexpr int MT_O = 208, MT_K = 128;
constexpr int MT_SZ = MT_O * MT_K;
constexpr int NB2 = 196;       // coarse dst buckets (dst>>8)
constexpr int BCAP = 2560;     // bucket capacity
constexpr int ECHK = 8;        // chunks per edgemm block; 7040/8=880 (div 8)
constexpr int BIN_EPB = 2048;  // edges per k_bin block
constexpr int BIN_THREADS = 512;

typedef short bf16x8 __attribute__((ext_vector_type(8)));
typedef float f32x4  __attribute__((ext_vector_type(4)));
typedef unsigned short ushort8 __attribute__((ext_vector_type(8)));
typedef __attribute__((address_space(1))) const unsigned int guint_t;
typedef __attribute__((address_space(3))) unsigned int luint_t;

__device__ inline unsigned short f2bf(float x) {
    unsigned u = __float_as_uint(x);
    u = (u + 0x7fffu + ((u >> 16) & 1u)) >> 16;
    return (unsigned short)u;
}
__device__ inline float bf2f(unsigned short u) {
    return __uint_as_float(((unsigned)u) << 16);
}

// ---------------- fused precompute + key-hist: Mloop | r_out | WT_bf | ent_bf | hist1
constexpr int G_MLOOP = (D * OUT + 255) / 256;       // 79
constexpr int G_ROUT  = (R * OUT + 255) / 256;       // 313
constexpr int G_CVTWT = (2 * 208 * 16) / 256;        // 26
constexpr int G_CVTENT = (V * 16) / 256;             // 3125
constexpr int G_HIST = 512;
constexpr int PRE_B1 = G_MLOOP;
constexpr int PRE_B2 = PRE_B1 + G_ROUT;
constexpr int PRE_B3 = PRE_B2 + G_CVTWT;
constexpr int PRE_B4 = PRE_B3 + G_CVTENT;
constexpr int PRE_NWG = PRE_B4 + G_HIST;

__global__ __launch_bounds__(256) void k_pre(const float* __restrict__ loop_rel,
                                             const float* __restrict__ loop_w,
                                             const float* __restrict__ rel_emb,
                                             const float* __restrict__ w_rel,
                                             const float* __restrict__ in_w,
                                             const float* __restrict__ out_w,
                                             const float* __restrict__ ent_emb,
                                             const int* __restrict__ etyp,
                                             float* __restrict__ Mloop,
                                             float* __restrict__ r_out,
                                             unsigned short* __restrict__ WT_bf,
                                             unsigned short* __restrict__ ent_bf,
                                             int* __restrict__ hist1) {
    __shared__ int lh[NKEY];
    int blk = blockIdx.x, t = threadIdx.x;
    if (blk < PRE_B1) {
        int i = blk * 256 + t;
        if (i >= D * OUT) return;
        int j = i / OUT, o = i % OUT;
        float s = 0.f;
        for (int k = 0; k < D; ++k) {
            int idx = j + k; if (idx >= D) idx -= D;
            s += loop_rel[idx] * loop_w[k * OUT + o];
        }
        Mloop[i] = s;
    } else if (blk < PRE_B2) {
        int i = (blk - PRE_B1) * 256 + t;
        if (i >= R * OUT) return;
        int r = i / OUT, o = i % OUT;
        float s = 0.f;
        for (int k = 0; k < D; ++k) s += rel_emb[r * D + k] * w_rel[k * OUT + o];
        r_out[i] = s;
    } else if (blk < PRE_B3) {
        int i = (blk - PRE_B2) * 256 + t;
        int side = i / (208 * 16);
        int rem = i - side * 208 * 16;
        int o = rem >> 4, c8 = rem & 15;
        int k0 = c8 * 8;
        const float* __restrict__ W = side ? out_w : in_w;
        ushort8 v = (ushort8)0;
        if (o < 200) {
#pragma unroll
            for (int q = 0; q < 8; ++q) {
                int k = k0 + q;
                if (k < 100) v[q] = f2bf(W[k * OUT + o]);
            }
        }
        *(ushort8*)&WT_bf[((size_t)side * 208 + o) * 128 + k0] = v;
    } else if (blk < PRE_B4) {
        int i = (blk - PRE_B3) * 256 + t;
        if (i >= V * 16) return;
        int v = i >> 4, c8 = i & 15;
        int c0 = c8 * 8;
        ushort8 o = (ushort8)0;
        if (c0 < 96) {
            float4 f0 = *(const float4*)&ent_emb[(size_t)v * D + c0];
            float4 f1 = *(const float4*)&ent_emb[(size_t)v * D + c0 + 4];
            o[0] = f2bf(f0.x); o[1] = f2bf(f0.y); o[2] = f2bf(f0.z); o[3] = f2bf(f0.w);
            o[4] = f2bf(f1.x); o[5] = f2bf(f1.y); o[6] = f2bf(f1.z); o[7] = f2bf(f1.w);
        } else if (c0 == 96) {
            float4 f0 = *(const float4*)&ent_emb[(size_t)v * D + 96];
            o[0] = f2bf(f0.x); o[1] = f2bf(f0.y); o[2] = f2bf(f0.z); o[3] = f2bf(f0.w);
        }
        *(ushort8*)&ent_bf[(size_t)v * 128 + c0] = o;
    } else {                                  // key histogram (LDS-aggregated)
        int hb = blk - PRE_B4;
        for (int i = t; i < NKEY; i += 256) lh[i] = 0;
        __syncthreads();
        for (int e = hb * 256 + t; e < E; e += G_HIST * 256) {
            int key = etyp[e] + (e < HALF ? 0 : R);
            atomicAdd(&lh[key], 1);
        }
        __syncthreads();
        for (int i = t; i < NKEY; i += 256) {
            int c = lh[i];
            if (c) atomicAdd(&hist1[i], c);
        }
    }
}

// ---------------- key scan (64-aligned buckets) + perm1 pad-tail fill
__global__ __launch_bounds__(1024) void k_scan(const int* __restrict__ hist1,
                                               int* __restrict__ start1,
                                               int* __restrict__ Edev,
                                               unsigned* __restrict__ perm1) {
    __shared__ int buf[1024];
    int t = threadIdx.x;
    int h = (t < NKEY) ? hist1[t] : 0;
    int c = (h + 63) & ~63;
    buf[t] = c; __syncthreads();
    for (int off = 1; off < 1024; off <<= 1) {
        int x = (t >= off) ? buf[t - off] : 0; __syncthreads();
        buf[t] += x; __syncthreads();
    }
    int s = buf[t] - c;
    if (t < NKEY) {
        start1[t] = s;
        for (int i = h; i < c; ++i) perm1[s + i] = 0xFFFFFFFFu;  // sentinel pad tail
    }
    if (t == NKEY - 1) { start1[NKEY] = buf[t]; *Edev = buf[t]; }
}

// ---------------- fused binning: perm1 scatter + dst pairs in ONE pass
__global__ __launch_bounds__(BIN_THREADS) void k_bin(const int* __restrict__ etyp,
                                                     const int* __restrict__ edst,
                                                     const int* __restrict__ start1,
                                                     int* __restrict__ cursor1,
                                                     int* __restrict__ cursor196,
                                                     unsigned* __restrict__ perm1,
                                                     uint2* __restrict__ pairs) {
    __shared__ int lhist[NKEY], lbase[NKEY], lcnt[NKEY];
    __shared__ int chist[NB2], cbase[NB2], ccnt[NB2];
    int t = threadIdx.x;
    int e0 = blockIdx.x * BIN_EPB;
    for (int i = t; i < NKEY; i += BIN_THREADS) { lhist[i] = 0; lcnt[i] = 0; }
    for (int i = t; i < NB2; i += BIN_THREADS) { chist[i] = 0; ccnt[i] = 0; }
    __syncthreads();
    for (int i = t; i < BIN_EPB; i += BIN_THREADS) {
        int e = e0 + i;
        if (e < E) {
            int key = etyp[e] + (e < HALF ? 0 : R);
            atomicAdd(&lhist[key], 1);
            atomicAdd(&chist[edst[e] >> 8], 1);
        }
    }
    __syncthreads();
    for (int i = t; i < NKEY; i += BIN_THREADS) {
        int c = lhist[i];
        lbase[i] = c ? (start1[i] + atomicAdd(&cursor1[i], c)) : 0;
    }
    for (int i = t; i < NB2; i += BIN_THREADS) {
        int c = chist[i];
        cbase[i] = c ? atomicAdd(&cursor196[i], c) : 0;
    }
    __syncthreads();
    for (int i = t; i < BIN_EPB; i += BIN_THREADS) {
        int e = e0 + i;
        if (e < E) {
            int key = etyp[e] + (e < HALF ? 0 : R);
            int r = atomicAdd(&lcnt[key], 1);
            int p = lbase[key] + r;
            perm1[p] = (unsigned)e | ((unsigned)key << 19);
            int d = edst[e];
            int ld = d >> 8;
            int rr = atomicAdd(&ccnt[ld], 1);
            int slot = cbase[ld] + rr;
            if (slot < BCAP)
                pairs[(size_t)ld * BCAP + slot] = make_uint2((unsigned)d, (unsigned)p);
        }
    }
}

// ---------------- fused: per-bucket dst ranking | Mt table build (MFMA)
constexpr int BD2MT_NWG = NB2 + NKEY;   // 196 + 800

__global__ __launch_bounds__(256) void k_bd2mt(const int* __restrict__ cursor196,
                                               const uint2* __restrict__ pairs,
                                               const float* __restrict__ rel_emb,
                                               const unsigned short* __restrict__ WT_bf,
                                               int* __restrict__ start2,
                                               int* __restrict__ poslist,
                                               unsigned short* __restrict__ Mtab) {
    int blk = blockIdx.x, t = threadIdx.x;
    if (blk < NB2) {   // ---- dst ranking
        __shared__ int lcnt[256], loff[256], lrk[256], bscan[256];
        int b = blk;
        lcnt[t] = 0; lrk[t] = 0;
        bscan[t] = (t < NB2) ? min(cursor196[t], BCAP) : 0;
        __syncthreads();
        for (int off = 1; off < 256; off <<= 1) {
            int xx = (t >= off) ? bscan[t - off] : 0; __syncthreads();
            bscan[t] += xx; __syncthreads();
        }
        int base = (b > 0) ? bscan[b - 1] : 0;
        if (b == 0 && t == 0) start2[V] = bscan[NB2 - 1];
        int n = min(cursor196[b], BCAP);
        for (int i = t; i < n; i += 256) {
            int d = (int)pairs[(size_t)b * BCAP + i].x;
            atomicAdd(&lcnt[d - (b << 8)], 1);
        }
        __syncthreads();
        int cc = lcnt[t];
        loff[t] = cc; __syncthreads();
        for (int off = 1; off < 256; off <<= 1) {
            int xx = (t >= off) ? loff[t - off] : 0; __syncthreads();
            loff[t] += xx; __syncthreads();
        }
        int excl = loff[t] - cc;
        loff[t] = excl;
        int d = (b << 8) + t;
        if (d < V) start2[d] = base + excl;
        __syncthreads();
        for (int i = t; i < n; i += 256) {
            uint2 pr = pairs[(size_t)b * BCAP + i];
            int ld = (int)pr.x - (b << 8);
            int r = atomicAdd(&lrk[ld], 1);
            poslist[base + loff[ld] + r] = (int)pr.y;
        }
    } else {           // ---- Mt[key] = WT_bf[side] @ Hankel(r) via MFMA
        __shared__ unsigned short rsh[256];
        int key = blk - NB2;
        int rho = (key < R) ? key : key - R;
        int side = (key < R) ? 0 : 1;
        int lane = t & 63, wid = t >> 6;
        {
            int sm = t;
            if (sm >= 200) sm -= 200; else if (sm >= 100) sm -= 100;
            rsh[t] = f2bf(rel_emb[rho * D + sm]);
        }
        __syncthreads();
        const unsigned short* WT = WT_bf + (size_t)side * 208 * 128;
        unsigned short* MtK = Mtab + (size_t)key * MT_SZ;
        int m16 = lane & 15, kq = lane >> 4;
        for (int jt = 0; jt < 2; ++jt) {
            int j0 = (wid * 2 + jt) * 16;
            f32x4 acc[13] = {};
            for (int ks = 0; ks < 4; ++ks) {
                int rbase = ks * 32 + kq * 8 + j0 + m16;   // max 254
                ushort8 tmp;
#pragma unroll
                for (int q = 0; q < 8; ++q) tmp[q] = rsh[rbase + q];
                bf16x8 bfr = *(bf16x8*)&tmp;
#pragma unroll
                for (int of = 0; of < 13; ++of) {
                    bf16x8 afr = *(const bf16x8*)&WT[(size_t)(of * 16 + m16) * 128 + ks * 32 + kq * 8];
                    acc[of] = __builtin_amdgcn_mfma_f32_16x16x32_bf16(afr, bfr, acc[of], 0, 0, 0);
                }
            }
#pragma unroll
            for (int of = 0; of < 13; ++of) {
                int orow = of * 16 + kq * 4;
#pragma unroll
                for (int q = 0; q < 4; ++q)
                    MtK[(size_t)(orow + q) * MT_K + j0 + m16] = f2bf(acc[of][q]);
            }
        }
    }
}

// ---------------- per-chunk MFMA with Mt reuse across 8 chunks per block
__global__ __launch_bounds__(256, 2) void k_edgemm(const unsigned* __restrict__ perm1,
                                                   const int* __restrict__ Edev,
                                                   const int* __restrict__ esrc,
                                                   const float* __restrict__ enorm,
                                                   const unsigned short* __restrict__ ent_bf,
                                                   const unsigned short* __restrict__ Mtab,
                                                   unsigned short* __restrict__ msg) {
    __shared__ __align__(16) unsigned short MtL[MT_SZ];      // 53,248 B
    __shared__ __align__(16) unsigned short AtL[64 * MT_K];  // 16,384 B
    __shared__ float snrm[2][64];
    __shared__ int ssrc[2][64];
    int t = threadIdx.x, lane = t & 63, wid = t >> 6;
    int cpx = gridDim.x >> 3;
    int blk = (blockIdx.x & 7) * cpx + (blockIdx.x >> 3);
    int nE = *Edev;
    int curkey = -1;
    for (int c = 0; c < ECHK; ++c) {
        int chunk = blk * ECHK + c;
        if (chunk * 64 >= nE) break;
        int buf = c & 1;
        if (t < 64) {
            unsigned val = perm1[chunk * 64 + t];
            int e = (int)(val & 0x7FFFFu);
            bool ok = (val != 0xFFFFFFFFu);
            ssrc[buf][t] = ok ? esrc[e] : 0;
            snrm[buf][t] = ok ? enorm[e] : 0.f;
        }
        int key = (int)(perm1[chunk * 64] >> 19);   // chunk base is always real
        __syncthreads();
        if (key != curkey) {
            for (int i = 0; i < 13; ++i) {
                int G0 = (wid * 13 + i) * 64;
                int G = G0 + lane;
                int o = G >> 4, g = G & 15;
                int gs = g ^ (o & 7);
                __builtin_amdgcn_global_load_lds(
                    (guint_t*)(Mtab + (size_t)key * MT_SZ + o * MT_K + gs * 8),
                    (luint_t*)(MtL + (size_t)G0 * 8), 16, 0, 0);
            }
            curkey = key;
        }
        for (int i = 0; i < 4; ++i) {
            int base = (wid * 4 + i) * 1024;
            int Gb = base + lane * 16;
            int row = Gb >> 8;
            int g = (Gb >> 4) & 15;
            int gs = g ^ (row & 7);
            __builtin_amdgcn_global_load_lds(
                (guint_t*)(ent_bf + (size_t)ssrc[buf][row] * 128 + gs * 8),
                (luint_t*)((char*)AtL + base), 16, 0, 0);
        }
        __syncthreads();
        int erow = wid * 16 + (lane & 15);
        int kq = lane >> 4;
        f32x4 acc[13] = {};
        for (int ks = 0; ks < 4; ++ks) {
            int g = ks * 4 + kq;
            bf16x8 bfr = *(const bf16x8*)((const char*)AtL + erow * 256 + ((g ^ (erow & 7)) * 16));
#pragma unroll
            for (int of = 0; of < 13; ++of) {
                int orow = of * 16 + (lane & 15);
                bf16x8 afr = *(const bf16x8*)((const char*)MtL + orow * 256 + ((g ^ (orow & 7)) * 16));
                acc[of] = __builtin_amdgcn_mfma_f32_16x16x32_bf16(afr, bfr, acc[of], 0, 0, 0);
            }
        }
        float nr = snrm[buf][erow];
        size_t rowbase = (size_t)(chunk * 64 + erow) * OUT;
#pragma unroll
        for (int of = 0; of < 13; ++of) {
            int o0 = of * 16 + kq * 4;
            if (o0 < OUT) {
                ushort4 pk;
                pk.x = f2bf(acc[of][0] * nr); pk.y = f2bf(acc[of][1] * nr);
                pk.z = f2bf(acc[of][2] * nr); pk.w = f2bf(acc[of][3] * nr);
                *(ushort4*)&msg[rowbase + o0] = pk;
            }
        }
    }
}

// ---------------- fused gather-sum + loop-term + bias -> x_bf (bf16)
__global__ __launch_bounds__(256) void k_aggx(const int* __restrict__ start2,
                                              const int* __restrict__ poslist,
                                              const unsigned short* __restrict__ msg,
                                              const float* __restrict__ ent_emb,
                                              const float* __restrict__ Mloop,
                                              const float* __restrict__ conv_bias,
                                              unsigned short* __restrict__ x_bf) {
    __shared__ float xt[16][200];
    __shared__ float sat[100][20];
    int t = threadIdx.x, lane = t & 63, wid = t >> 6;
    int v0 = blockIdx.x * 16;
    int half = (lane >= 25 && lane < 50) ? 1 : 0;
    int c = lane - half * 25;
    bool act = lane < 50;
    int src = lane + 25 < 64 ? lane + 25 : 63;
    for (int i = 0; i < 4; ++i) {
        int v = v0 + wid * 4 + i;
        int s = start2[v], epos = start2[v + 1];
        float acc[8] = {};
        for (int q = s; q < epos; q += 2) {
            int qq = q + half;
            if (act && qq < epos) {
                int p = poslist[qq];
                ushort8 m = *(const ushort8*)&msg[(size_t)p * OUT + c * 8];
#pragma unroll
                for (int j = 0; j < 8; ++j) acc[j] += bf2f(m[j]);
            }
        }
#pragma unroll
        for (int j = 0; j < 8; ++j) {
            float o = __shfl(acc[j], src);
            if (lane < 25) acc[j] += o;
        }
        if (lane < 25) {
#pragma unroll
            for (int j = 0; j < 8; ++j) xt[wid * 4 + i][lane * 8 + j] = acc[j];
        }
    }
    for (int i = t; i < 400; i += 256) {
        int kg = i >> 4, vv = i & 15;
        float4 a4 = *(const float4*)&ent_emb[(size_t)(v0 + vv) * D + kg * 4];
        sat[kg * 4 + 0][vv] = a4.x;
        sat[kg * 4 + 1][vv] = a4.y;
        sat[kg * 4 + 2][vv] = a4.z;
        sat[kg * 4 + 3][vv] = a4.w;
    }
    __syncthreads();
    if (t < 200) {
        int og = t % 50, eg = t / 50;
        int o0 = og * 4, vv0 = eg * 4;
        float acc[4][4] = {};
        for (int k = 0; k < D; ++k) {
            float4 w4 = *(const float4*)&Mloop[k * OUT + o0];
            float4 ca = *(const float4*)&sat[k][vv0];
            float cc[4] = {ca.x, ca.y, ca.z, ca.w};
            float wv[4] = {w4.x, w4.y, w4.z, w4.w};
#pragma unroll
            for (int r = 0; r < 4; ++r)
#pragma unroll
                for (int j = 0; j < 4; ++j) acc[r][j] += cc[r] * wv[j];
        }
        float4 bi = *(const float4*)&conv_bias[o0];
        float bv[4] = {bi.x, bi.y, bi.z, bi.w};
#pragma unroll
        for (int r = 0; r < 4; ++r) {
            int vv = vv0 + r;
            ushort4 ov;
            ov.x = f2bf((xt[vv][o0 + 0] + acc[r][0]) * (1.f / 3.f) + bv[0]);
            ov.y = f2bf((xt[vv][o0 + 1] + acc[r][1]) * (1.f / 3.f) + bv[1]);
            ov.z = f2bf((xt[vv][o0 + 2] + acc[r][2]) * (1.f / 3.f) + bv[2]);
            ov.w = f2bf((xt[vv][o0 + 3] + acc[r][3]) * (1.f / 3.f) + bv[3]);
            *(ushort4*)&x_bf[(size_t)(v0 + vv) * OUT + o0] = ov;
        }
    }
}

// ---------------- fused: BN stats (bf16 x) | emb fragment-packed conversion
constexpr int G_STATS = 400;
constexpr int G_PKEMB = (NTILE * 448) / 256;    // 5488
constexpr int STCV_NWG = G_STATS + G_PKEMB;

__global__ __launch_bounds__(256) void k_stcv(const unsigned short* __restrict__ x_bf,
                                              const float* __restrict__ emb_ent,
                                              float* __restrict__ colsum,
                                              float* __restrict__ colsq,
                                              unsigned short* __restrict__ emb_pk) {
    int blk = blockIdx.x, t = threadIdx.x;
    if (blk < G_STATS) {
        int g = blk * 256 + t;
        int col = g % OUT;
        int r0 = g / OUT;
        float s = 0.f, sq = 0.f;
        for (int r = r0; r < V; r += 512) {
            float v = bf2f(x_bf[(size_t)r * OUT + col]);
            s += v;
            sq += v * v;
        }
        atomicAdd(&colsum[col], s);
        atomicAdd(&colsq[col], sq);
    } else {
        int i = (blk - G_STATS) * 256 + t;
        if (i >= NTILE * 448) return;
        int vt = i / 448, r = i - vt * 448;
        int lane = r & 63;
        int ks = r >> 6;
        int v = vt * 16 + (lane & 15);
        int k0 = ks * 32 + (lane >> 4) * 8;
        ushort8 o = (ushort8)0;
        if (v < V && k0 < 200) {
            float4 f0 = *(const float4*)&emb_ent[(size_t)v * OUT + k0];
            float4 f1 = *(const float4*)&emb_ent[(size_t)v * OUT + k0 + 4];
            o[0] = f2bf(f0.x); o[1] = f2bf(f0.y); o[2] = f2bf(f0.z); o[3] = f2bf(f0.w);
            o[4] = f2bf(f1.x); o[5] = f2bf(f1.y); o[6] = f2bf(f1.z); o[7] = f2bf(f1.w);
        }
        *(ushort8*)&emb_pk[(size_t)i * 8] = o;
    }
}

// ---------------- obj_bf (inline mean/rstd; reads bf16 x)
__global__ __launch_bounds__(256) void k_obj(const int* __restrict__ head,
                                             const int* __restrict__ rela,
                                             const unsigned short* __restrict__ x_bf,
                                             const float* __restrict__ colsum,
                                             const float* __restrict__ colsq,
                                             const float* __restrict__ gamma,
                                             const float* __restrict__ beta,
                                             const float* __restrict__ r_out,
                                             unsigned short* __restrict__ obj_bf) {
    int b = blockIdx.x, t = threadIdx.x;
    if (t >= K2) return;
    float v = 0.f;
    if (t < OUT) {
        float m = colsum[t] / (float)V;
        float var = colsq[t] / (float)V - m * m;
        float rs = rsqrtf(var + EPS);
        int h = head[b], r = rela[b];
        float val = (bf2f(x_bf[(size_t)h * OUT + t]) - m) * rs * gamma[t] + beta[t];
        val = tanhf(val);
        v = val * r_out[r * OUT + t];
    }
    obj_bf[(size_t)b * K2 + t] = f2bf(v);
}

// ---------------- decoder: LDS-free MFMA GEMM, B from fragment-packed emb
constexpr int DEC_BM = 64, DEC_BN = 256;
constexpr int DEC_GX = B / DEC_BM;          // 16
constexpr int DEC_GY = VPAD / DEC_BN;       // 196
constexpr int DEC_NWG = DEC_GX * DEC_GY;    // 3136 (div by 8)

__global__ __launch_bounds__(256) void k_dec2(const unsigned short* __restrict__ obj_bf,
                                              const unsigned short* __restrict__ emb_pk,
                                              const float* __restrict__ ent_bias,
                                              float* __restrict__ score) {
    int t = threadIdx.x;
    int lane = t & 63, wid = t >> 6;
    int wg = (blockIdx.x & 7) * (DEC_NWG >> 3) + (blockIdx.x >> 3);
    int b0 = (wg & (DEC_GX - 1)) * DEC_BM;
    int v0 = (wg >> 4) * DEC_BN;
    int r16 = lane & 15;
    int kc = (lane >> 4) * 8;
    int vbase = v0 + wid * 64;
    int vtbase = vbase >> 4;
    const unsigned short* gA = obj_bf + (size_t)(b0 + r16) * K2 + kc;
    f32x4 acc[4][4] = {};
    for (int ks = 0; ks < 7; ++ks) {
        int kof = ks * 32;
        bf16x8 a[4], bb[4];
#pragma unroll
        for (int mf = 0; mf < 4; ++mf)
            a[mf] = *(const bf16x8*)(gA + (size_t)(mf * 16) * K2 + kof);
#pragma unroll
        for (int nf = 0; nf < 4; ++nf)
            bb[nf] = *(const bf16x8*)&emb_pk[(((size_t)(vtbase + nf) * 7 + ks) * 64 + lane) * 8];
#pragma unroll
        for (int mf = 0; mf < 4; ++mf)
#pragma unroll
            for (int nf = 0; nf < 4; ++nf)
                acc[mf][nf] = __builtin_amdgcn_mfma_f32_16x16x32_bf16(a[mf], bb[nf],
                                                                      acc[mf][nf], 0, 0, 0);
    }
#pragma unroll
    for (int nf = 0; nf < 4; ++nf) {
        int v = vbase + nf * 16 + r16;
        if (v >= V) continue;
        float bias = ent_bias[v];
#pragma unroll
        for (int mf = 0; mf < 4; ++mf) {
            int brow = b0 + mf * 16 + (lane >> 4) * 4;
            f32x4 av = acc[mf][nf];
#pragma unroll
            for (int i = 0; i < 4; ++i) {
                float val = av[i] + bias;
                score[(size_t)(brow + i) * V + v] = 1.f / (1.f + __expf(-val));
            }
        }
    }
}

extern "C" void kernel_launch(void* const* d_in, const int* in_sizes, int n_in,
                              void* d_out, int out_size, void* d_ws, size_t ws_size,
                              hipStream_t stream) {
    const int*   edge_src  = (const int*)d_in[0];
    const int*   edge_dst  = (const int*)d_in[1];
    const int*   edge_type = (const int*)d_in[2];
    const int*   head      = (const int*)d_in[3];
    const int*   rela      = (const int*)d_in[4];
    const float* edge_norm = (const float*)d_in[5];
    const float* ent_emb   = (const float*)d_in[6];
    const float* rel_emb   = (const float*)d_in[7];
    const float* in_w      = (const float*)d_in[8];
    const float* out_w     = (const float*)d_in[9];
    const float* loop_w    = (const float*)d_in[10];
    const float* w_rel     = (const float*)d_in[11];
    const float* loop_rel  = (const float*)d_in[12];
    const float* conv_bias = (const float*)d_in[13];
    const float* bn_gamma  = (const float*)d_in[14];
    const float* bn_beta   = (const float*)d_in[15];
    const float* emb_ent   = (const float*)d_in[16];
    const float* ent_bias  = (const float*)d_in[17];
    float* score = (float*)d_out;

    // ---- workspace layout
    char* w = (char*)d_ws;
    char*           base0  = w;                              w += (size_t)V * OUT * 4;   // 40 MB region
    unsigned short* Mtab   = (unsigned short*)w;             w += (size_t)NKEY * MT_SZ * 2;  // 42.6 MB
    unsigned*       perm1  = (unsigned*)w;                   w += (size_t)E1MAX * 4;
    int*            poslist  = (int*)w;                      w += (size_t)E * 4;
    uint2*          pairs    = (uint2*)w;                    w += (size_t)NB2 * BCAP * 8;
    char* zbase = w;
    int*   hist1     = (int*)w;                              w += NKEY * 4;
    int*   cursor1   = (int*)w;                              w += NKEY * 4;
    int*   cursor196 = (int*)w;                              w += NB2 * 4;
    float* colsum    = (float*)w;                            w += OUT * 4;
    float* colsq     = (float*)w;                            w += OUT * 4;
    size_t zbytes = (size_t)(w - zbase);
    int*   start1  = (int*)w;                                w += (NKEY + 1) * 4;
    int*   start2  = (int*)w;                                w += (V + 4) * 4;
    int*   Edev    = (int*)w;                                w += 16;
    float* Mloop   = (float*)w;                              w += (size_t)D * OUT * 4;
    float* r_out   = (float*)w;                              w += (size_t)R * OUT * 4;
    unsigned short* obj_bf = (unsigned short*)w;             w += (size_t)B * K2 * 2;
    unsigned short* WT_bf  = (unsigned short*)w;             w += (size_t)2 * 208 * 128 * 2;
    // overlays (strictly stream-ordered):
    unsigned short* ent_bf = (unsigned short*)base0; // V*128 ushorts; dead after k_edgemm
    unsigned short* x_bf   = (unsigned short*)base0; // V*200 ushorts; written by k_aggx (after k_edgemm)
    unsigned short* emb_pk = (unsigned short*)Mtab;  // NTILE*448*8 ushorts; Mtab dead after k_edgemm
    unsigned short* msg    = (unsigned short*)d_out; // E1MAX*200 ushorts; dead after k_aggx

    (void)hipMemsetAsync(zbase, 0, zbytes, stream);

    k_pre<<<PRE_NWG, 256, 0, stream>>>(loop_rel, loop_w, rel_emb, w_rel, in_w, out_w,
                                       ent_emb, edge_type, Mloop, r_out, WT_bf, ent_bf,
                                       hist1);
    k_scan<<<1, 1024, 0, stream>>>(hist1, start1, Edev, perm1);
    k_bin<<<(E + BIN_EPB - 1) / BIN_EPB, BIN_THREADS, 0, stream>>>(
        edge_type, edge_dst, start1, cursor1, cursor196, perm1, pairs);
    k_bd2mt<<<BD2MT_NWG, 256, 0, stream>>>(cursor196, pairs, rel_emb, WT_bf,
                                           start2, poslist, Mtab);
    k_edgemm<<<E1MAX / 64 / ECHK, 256, 0, stream>>>(perm1, Edev, edge_src, edge_norm,
                                                    ent_bf, Mtab, msg);
    k_aggx<<<V / 16, 256, 0, stream>>>(start2, poslist, msg, ent_emb, Mloop,
                                       conv_bias, x_bf);
    k_stcv<<<STCV_NWG, 256, 0, stream>>>(x_bf, emb_ent, colsum, colsq, emb_pk);
    k_obj<<<B, 256, 0, stream>>>(head, rela, x_bf, colsum, colsq, bn_gamma, bn_beta,
                                 r_out, obj_bf);
    k_dec2<<<DEC_NWG, 256, 0, stream>>>(obj_bf, emb_pk, ent_bias, score);
}

// Round 17
// 379.086 us; speedup vs baseline: 1.0824x; 1.0260x over previous
//
#include <hip/hip_runtime.h>
#include <cstddef>

constexpr int V = 50000, E = 400000, R = 400, D = 100, OUT = 200, B = 1024;
constexpr int HALF = E / 2;
constexpr float EPS = 1e-5f;
constexpr int K2 = 232;        // obj K pad (bf16)
constexpr int VPAD = 50176;    // 196*256
constexpr int NTILE = VPAD / 16;  // 3136 v-tiles for packed emb
constexpr int NKEY = 800;      // (rel, side)
constexpr int E1MAX = 450560;  // E + NKEY*63 rounded up; /64 = 7040 chunks
constexpr int MT_O = 208, MT_K = 128;
constexpr int MT_SZ = MT_O * MT_K;
constexpr int NB2 = 196;       // coarse dst buckets (dst>>8)
constexpr int BCAP = 2560;     // bucket capacity
constexpr int ECHK = 8;        // chunks per edgemm block; 7040/8=880 (div 8)
constexpr int BIN_EPB = 2048;  // edges per k_bin block
constexpr int BIN_THREADS = 512;

typedef short bf16x8 __attribute__((ext_vector_type(8)));
typedef float f32x4  __attribute__((ext_vector_type(4)));
typedef unsigned short ushort8 __attribute__((ext_vector_type(8)));
typedef __attribute__((address_space(1))) const unsigned int guint_t;
typedef __attribute__((address_space(3))) unsigned int luint_t;

__device__ inline unsigned short f2bf(float x) {
    unsigned u = __float_as_uint(x);
    u = (u + 0x7fffu + ((u >> 16) & 1u)) >> 16;
    return (unsigned short)u;
}
__device__ inline float bf2f(unsigned short u) {
    return __uint_as_float(((unsigned)u) << 16);
}

// ---------------- fused precompute + key-hist: Mloop | r_out | WT_bf | ent_bf | hist1
constexpr int G_MLOOP = (D * OUT + 255) / 256;       // 79
constexpr int G_ROUT  = (R * OUT + 255) / 256;       // 313
constexpr int G_CVTWT = (2 * 208 * 16) / 256;        // 26
constexpr int G_CVTENT = (V * 16) / 256;             // 3125
constexpr int G_HIST = 512;
constexpr int PRE_B1 = G_MLOOP;
constexpr int PRE_B2 = PRE_B1 + G_ROUT;
constexpr int PRE_B3 = PRE_B2 + G_CVTWT;
constexpr int PRE_B4 = PRE_B3 + G_CVTENT;
constexpr int PRE_NWG = PRE_B4 + G_HIST;

__global__ __launch_bounds__(256) void k_pre(const float* __restrict__ loop_rel,
                                             const float* __restrict__ loop_w,
                                             const float* __restrict__ rel_emb,
                                             const float* __restrict__ w_rel,
                                             const float* __restrict__ in_w,
                                             const float* __restrict__ out_w,
                                             const float* __restrict__ ent_emb,
                                             const int* __restrict__ etyp,
                                             float* __restrict__ Mloop,
                                             float* __restrict__ r_out,
                                             unsigned short* __restrict__ WT_bf,
                                             unsigned short* __restrict__ ent_bf,
                                             int* __restrict__ hist1) {
    __shared__ int lh[NKEY];
    int blk = blockIdx.x, t = threadIdx.x;
    if (blk < PRE_B1) {
        int i = blk * 256 + t;
        if (i >= D * OUT) return;
        int j = i / OUT, o = i % OUT;
        float s = 0.f;
        for (int k = 0; k < D; ++k) {
            int idx = j + k; if (idx >= D) idx -= D;
            s += loop_rel[idx] * loop_w[k * OUT + o];
        }
        Mloop[i] = s;
    } else if (blk < PRE_B2) {
        int i = (blk - PRE_B1) * 256 + t;
        if (i >= R * OUT) return;
        int r = i / OUT, o = i % OUT;
        float s = 0.f;
        for (int k = 0; k < D; ++k) s += rel_emb[r * D + k] * w_rel[k * OUT + o];
        r_out[i] = s;
    } else if (blk < PRE_B3) {
        int i = (blk - PRE_B2) * 256 + t;
        int side = i / (208 * 16);
        int rem = i - side * 208 * 16;
        int o = rem >> 4, c8 = rem & 15;
        int k0 = c8 * 8;
        const float* __restrict__ W = side ? out_w : in_w;
        ushort8 v = (ushort8)0;
        if (o < 200) {
#pragma unroll
            for (int q = 0; q < 8; ++q) {
                int k = k0 + q;
                if (k < 100) v[q] = f2bf(W[k * OUT + o]);
            }
        }
        *(ushort8*)&WT_bf[((size_t)side * 208 + o) * 128 + k0] = v;
    } else if (blk < PRE_B4) {
        int i = (blk - PRE_B3) * 256 + t;
        if (i >= V * 16) return;
        int v = i >> 4, c8 = i & 15;
        int c0 = c8 * 8;
        ushort8 o = (ushort8)0;
        if (c0 < 96) {
            float4 f0 = *(const float4*)&ent_emb[(size_t)v * D + c0];
            float4 f1 = *(const float4*)&ent_emb[(size_t)v * D + c0 + 4];
            o[0] = f2bf(f0.x); o[1] = f2bf(f0.y); o[2] = f2bf(f0.z); o[3] = f2bf(f0.w);
            o[4] = f2bf(f1.x); o[5] = f2bf(f1.y); o[6] = f2bf(f1.z); o[7] = f2bf(f1.w);
        } else if (c0 == 96) {
            float4 f0 = *(const float4*)&ent_emb[(size_t)v * D + 96];
            o[0] = f2bf(f0.x); o[1] = f2bf(f0.y); o[2] = f2bf(f0.z); o[3] = f2bf(f0.w);
        }
        *(ushort8*)&ent_bf[(size_t)v * 128 + c0] = o;
    } else {                                  // key histogram (LDS-aggregated)
        int hb = blk - PRE_B4;
        for (int i = t; i < NKEY; i += 256) lh[i] = 0;
        __syncthreads();
        for (int e = hb * 256 + t; e < E; e += G_HIST * 256) {
            int key = etyp[e] + (e < HALF ? 0 : R);
            atomicAdd(&lh[key], 1);
        }
        __syncthreads();
        for (int i = t; i < NKEY; i += 256) {
            int c = lh[i];
            if (c) atomicAdd(&hist1[i], c);
        }
    }
}

// ---------------- key scan (64-aligned buckets) + perm1 pad-tail fill
__global__ __launch_bounds__(1024) void k_scan(const int* __restrict__ hist1,
                                               int* __restrict__ start1,
                                               int* __restrict__ Edev,
                                               unsigned* __restrict__ perm1) {
    __shared__ int buf[1024];
    int t = threadIdx.x;
    int h = (t < NKEY) ? hist1[t] : 0;
    int c = (h + 63) & ~63;
    buf[t] = c; __syncthreads();
    for (int off = 1; off < 1024; off <<= 1) {
        int x = (t >= off) ? buf[t - off] : 0; __syncthreads();
        buf[t] += x; __syncthreads();
    }
    int s = buf[t] - c;
    if (t < NKEY) {
        start1[t] = s;
        for (int i = h; i < c; ++i) perm1[s + i] = 0xFFFFFFFFu;  // sentinel pad tail
    }
    if (t == NKEY - 1) { start1[NKEY] = buf[t]; *Edev = buf[t]; }
}

// ---------------- fused binning: perm1 scatter + dst pairs in ONE pass
__global__ __launch_bounds__(BIN_THREADS) void k_bin(const int* __restrict__ etyp,
                                                     const int* __restrict__ edst,
                                                     const int* __restrict__ start1,
                                                     int* __restrict__ cursor1,
                                                     int* __restrict__ cursor196,
                                                     unsigned* __restrict__ perm1,
                                                     uint2* __restrict__ pairs) {
    __shared__ int lhist[NKEY], lbase[NKEY], lcnt[NKEY];
    __shared__ int chist[NB2], cbase[NB2], ccnt[NB2];
    int t = threadIdx.x;
    int e0 = blockIdx.x * BIN_EPB;
    for (int i = t; i < NKEY; i += BIN_THREADS) { lhist[i] = 0; lcnt[i] = 0; }
    for (int i = t; i < NB2; i += BIN_THREADS) { chist[i] = 0; ccnt[i] = 0; }
    __syncthreads();
    for (int i = t; i < BIN_EPB; i += BIN_THREADS) {
        int e = e0 + i;
        if (e < E) {
            int key = etyp[e] + (e < HALF ? 0 : R);
            atomicAdd(&lhist[key], 1);
            atomicAdd(&chist[edst[e] >> 8], 1);
        }
    }
    __syncthreads();
    for (int i = t; i < NKEY; i += BIN_THREADS) {
        int c = lhist[i];
        lbase[i] = c ? (start1[i] + atomicAdd(&cursor1[i], c)) : 0;
    }
    for (int i = t; i < NB2; i += BIN_THREADS) {
        int c = chist[i];
        cbase[i] = c ? atomicAdd(&cursor196[i], c) : 0;
    }
    __syncthreads();
    for (int i = t; i < BIN_EPB; i += BIN_THREADS) {
        int e = e0 + i;
        if (e < E) {
            int key = etyp[e] + (e < HALF ? 0 : R);
            int r = atomicAdd(&lcnt[key], 1);
            int p = lbase[key] + r;
            perm1[p] = (unsigned)e | ((unsigned)key << 19);
            int d = edst[e];
            int ld = d >> 8;
            int rr = atomicAdd(&ccnt[ld], 1);
            int slot = cbase[ld] + rr;
            if (slot < BCAP)
                pairs[(size_t)ld * BCAP + slot] = make_uint2((unsigned)d, (unsigned)p);
        }
    }
}

// ---------------- fused: per-bucket dst ranking | Mt table build (MFMA)
constexpr int BD2MT_NWG = NB2 + NKEY;   // 196 + 800

__global__ __launch_bounds__(256) void k_bd2mt(const int* __restrict__ cursor196,
                                               const uint2* __restrict__ pairs,
                                               const float* __restrict__ rel_emb,
                                               const unsigned short* __restrict__ WT_bf,
                                               int* __restrict__ start2,
                                               int* __restrict__ poslist,
                                               unsigned short* __restrict__ Mtab) {
    int blk = blockIdx.x, t = threadIdx.x;
    if (blk < NB2) {   // ---- dst ranking
        __shared__ int lcnt[256], loff[256], lrk[256], bscan[256];
        int b = blk;
        lcnt[t] = 0; lrk[t] = 0;
        bscan[t] = (t < NB2) ? min(cursor196[t], BCAP) : 0;
        __syncthreads();
        for (int off = 1; off < 256; off <<= 1) {
            int xx = (t >= off) ? bscan[t - off] : 0; __syncthreads();
            bscan[t] += xx; __syncthreads();
        }
        int base = (b > 0) ? bscan[b - 1] : 0;
        if (b == 0 && t == 0) start2[V] = bscan[NB2 - 1];
        int n = min(cursor196[b], BCAP);
        for (int i = t; i < n; i += 256) {
            int d = (int)pairs[(size_t)b * BCAP + i].x;
            atomicAdd(&lcnt[d - (b << 8)], 1);
        }
        __syncthreads();
        int cc = lcnt[t];
        loff[t] = cc; __syncthreads();
        for (int off = 1; off < 256; off <<= 1) {
            int xx = (t >= off) ? loff[t - off] : 0; __syncthreads();
            loff[t] += xx; __syncthreads();
        }
        int excl = loff[t] - cc;
        loff[t] = excl;
        int d = (b << 8) + t;
        if (d < V) start2[d] = base + excl;
        __syncthreads();
        for (int i = t; i < n; i += 256) {
            uint2 pr = pairs[(size_t)b * BCAP + i];
            int ld = (int)pr.x - (b << 8);
            int r = atomicAdd(&lrk[ld], 1);
            poslist[base + loff[ld] + r] = (int)pr.y;
        }
    } else {           // ---- Mt[key] = WT_bf[side] @ Hankel(r) via MFMA
        __shared__ unsigned short rsh[256];
        int key = blk - NB2;
        int rho = (key < R) ? key : key - R;
        int side = (key < R) ? 0 : 1;
        int lane = t & 63, wid = t >> 6;
        {
            int sm = t;
            if (sm >= 200) sm -= 200; else if (sm >= 100) sm -= 100;
            rsh[t] = f2bf(rel_emb[rho * D + sm]);
        }
        __syncthreads();
        const unsigned short* WT = WT_bf + (size_t)side * 208 * 128;
        unsigned short* MtK = Mtab + (size_t)key * MT_SZ;
        int m16 = lane & 15, kq = lane >> 4;
        for (int jt = 0; jt < 2; ++jt) {
            int j0 = (wid * 2 + jt) * 16;
            f32x4 acc[13] = {};
            for (int ks = 0; ks < 4; ++ks) {
                int rbase = ks * 32 + kq * 8 + j0 + m16;   // max 254
                ushort8 tmp;
#pragma unroll
                for (int q = 0; q < 8; ++q) tmp[q] = rsh[rbase + q];
                bf16x8 bfr = *(bf16x8*)&tmp;
#pragma unroll
                for (int of = 0; of < 13; ++of) {
                    bf16x8 afr = *(const bf16x8*)&WT[(size_t)(of * 16 + m16) * 128 + ks * 32 + kq * 8];
                    acc[of] = __builtin_amdgcn_mfma_f32_16x16x32_bf16(afr, bfr, acc[of], 0, 0, 0);
                }
            }
#pragma unroll
            for (int of = 0; of < 13; ++of) {
                int orow = of * 16 + kq * 4;
#pragma unroll
                for (int q = 0; q < 4; ++q)
                    MtK[(size_t)(orow + q) * MT_K + j0 + m16] = f2bf(acc[of][q]);
            }
        }
    }
}

// ---------------- per-chunk MFMA with Mt reuse across 8 chunks per block
__global__ __launch_bounds__(256, 2) void k_edgemm(const unsigned* __restrict__ perm1,
                                                   const int* __restrict__ Edev,
                                                   const int* __restrict__ esrc,
                                                   const float* __restrict__ enorm,
                                                   const unsigned short* __restrict__ ent_bf,
                                                   const unsigned short* __restrict__ Mtab,
                                                   unsigned short* __restrict__ msg) {
    __shared__ __align__(16) unsigned short MtL[MT_SZ];      // 53,248 B
    __shared__ __align__(16) unsigned short AtL[64 * MT_K];  // 16,384 B
    __shared__ float snrm[2][64];
    __shared__ int ssrc[2][64];
    int t = threadIdx.x, lane = t & 63, wid = t >> 6;
    int cpx = gridDim.x >> 3;
    int blk = (blockIdx.x & 7) * cpx + (blockIdx.x >> 3);
    int nE = *Edev;
    int curkey = -1;
    for (int c = 0; c < ECHK; ++c) {
        int chunk = blk * ECHK + c;
        if (chunk * 64 >= nE) break;
        int buf = c & 1;
        if (t < 64) {
            unsigned val = perm1[chunk * 64 + t];
            int e = (int)(val & 0x7FFFFu);
            bool ok = (val != 0xFFFFFFFFu);
            ssrc[buf][t] = ok ? esrc[e] : 0;
            snrm[buf][t] = ok ? enorm[e] : 0.f;
        }
        int key = (int)(perm1[chunk * 64] >> 19);   // chunk base is always real
        __syncthreads();
        if (key != curkey) {
            for (int i = 0; i < 13; ++i) {
                int G0 = (wid * 13 + i) * 64;
                int G = G0 + lane;
                int o = G >> 4, g = G & 15;
                int gs = g ^ (o & 7);
                __builtin_amdgcn_global_load_lds(
                    (guint_t*)(Mtab + (size_t)key * MT_SZ + o * MT_K + gs * 8),
                    (luint_t*)(MtL + (size_t)G0 * 8), 16, 0, 0);
            }
            curkey = key;
        }
        for (int i = 0; i < 4; ++i) {
            int base = (wid * 4 + i) * 1024;
            int Gb = base + lane * 16;
            int row = Gb >> 8;
            int g = (Gb >> 4) & 15;
            int gs = g ^ (row & 7);
            __builtin_amdgcn_global_load_lds(
                (guint_t*)(ent_bf + (size_t)ssrc[buf][row] * 128 + gs * 8),
                (luint_t*)((char*)AtL + base), 16, 0, 0);
        }
        __syncthreads();
        int erow = wid * 16 + (lane & 15);
        int kq = lane >> 4;
        f32x4 acc[13] = {};
        for (int ks = 0; ks < 4; ++ks) {
            int g = ks * 4 + kq;
            bf16x8 bfr = *(const bf16x8*)((const char*)AtL + erow * 256 + ((g ^ (erow & 7)) * 16));
#pragma unroll
            for (int of = 0; of < 13; ++of) {
                int orow = of * 16 + (lane & 15);
                bf16x8 afr = *(const bf16x8*)((const char*)MtL + orow * 256 + ((g ^ (orow & 7)) * 16));
                acc[of] = __builtin_amdgcn_mfma_f32_16x16x32_bf16(afr, bfr, acc[of], 0, 0, 0);
            }
        }
        float nr = snrm[buf][erow];
        size_t rowbase = (size_t)(chunk * 64 + erow) * OUT;
#pragma unroll
        for (int of = 0; of < 13; ++of) {
            int o0 = of * 16 + kq * 4;
            if (o0 < OUT) {
                ushort4 pk;
                pk.x = f2bf(acc[of][0] * nr); pk.y = f2bf(acc[of][1] * nr);
                pk.z = f2bf(acc[of][2] * nr); pk.w = f2bf(acc[of][3] * nr);
                *(ushort4*)&msg[rowbase + o0] = pk;
            }
        }
    }
}

// ---------------- fused gather-sum + loop-term + bias -> x_bf (bf16)
__global__ __launch_bounds__(256) void k_aggx(const int* __restrict__ start2,
                                              const int* __restrict__ poslist,
                                              const unsigned short* __restrict__ msg,
                                              const float* __restrict__ ent_emb,
                                              const float* __restrict__ Mloop,
                                              const float* __restrict__ conv_bias,
                                              unsigned short* __restrict__ x_bf) {
    __shared__ float xt[16][200];
    __shared__ float sat[100][20];
    int t = threadIdx.x, lane = t & 63, wid = t >> 6;
    int v0 = blockIdx.x * 16;
    int half = (lane >= 25 && lane < 50) ? 1 : 0;
    int c = lane - half * 25;
    bool act = lane < 50;
    int src = lane + 25 < 64 ? lane + 25 : 63;
    for (int i = 0; i < 4; ++i) {
        int v = v0 + wid * 4 + i;
        int s = start2[v], epos = start2[v + 1];
        float acc[8] = {};
        for (int q = s; q < epos; q += 2) {
            int qq = q + half;
            if (act && qq < epos) {
                int p = poslist[qq];
                ushort8 m = *(const ushort8*)&msg[(size_t)p * OUT + c * 8];
#pragma unroll
                for (int j = 0; j < 8; ++j) acc[j] += bf2f(m[j]);
            }
        }
#pragma unroll
        for (int j = 0; j < 8; ++j) {
            float o = __shfl(acc[j], src);
            if (lane < 25) acc[j] += o;
        }
        if (lane < 25) {
#pragma unroll
            for (int j = 0; j < 8; ++j) xt[wid * 4 + i][lane * 8 + j] = acc[j];
        }
    }
    for (int i = t; i < 400; i += 256) {
        int kg = i >> 4, vv = i & 15;
        float4 a4 = *(const float4*)&ent_emb[(size_t)(v0 + vv) * D + kg * 4];
        sat[kg * 4 + 0][vv] = a4.x;
        sat[kg * 4 + 1][vv] = a4.y;
        sat[kg * 4 + 2][vv] = a4.z;
        sat[kg * 4 + 3][vv] = a4.w;
    }
    __syncthreads();
    if (t < 200) {
        int og = t % 50, eg = t / 50;
        int o0 = og * 4, vv0 = eg * 4;
        float acc[4][4] = {};
        for (int k = 0; k < D; ++k) {
            float4 w4 = *(const float4*)&Mloop[k * OUT + o0];
            float4 ca = *(const float4*)&sat[k][vv0];
            float cc[4] = {ca.x, ca.y, ca.z, ca.w};
            float wv[4] = {w4.x, w4.y, w4.z, w4.w};
#pragma unroll
            for (int r = 0; r < 4; ++r)
#pragma unroll
                for (int j = 0; j < 4; ++j) acc[r][j] += cc[r] * wv[j];
        }
        float4 bi = *(const float4*)&conv_bias[o0];
        float bv[4] = {bi.x, bi.y, bi.z, bi.w};
#pragma unroll
        for (int r = 0; r < 4; ++r) {
            int vv = vv0 + r;
            ushort4 ov;
            ov.x = f2bf((xt[vv][o0 + 0] + acc[r][0]) * (1.f / 3.f) + bv[0]);
            ov.y = f2bf((xt[vv][o0 + 1] + acc[r][1]) * (1.f / 3.f) + bv[1]);
            ov.z = f2bf((xt[vv][o0 + 2] + acc[r][2]) * (1.f / 3.f) + bv[2]);
            ov.w = f2bf((xt[vv][o0 + 3] + acc[r][3]) * (1.f / 3.f) + bv[3]);
            *(ushort4*)&x_bf[(size_t)(v0 + vv) * OUT + o0] = ov;
        }
    }
}

// ---------------- fused: BN stats (vectorized bf16x8 + LDS reduce) | emb packing
constexpr int G_STATS = 400;
constexpr int G_PKEMB = (NTILE * 448) / 256;    // 5488
constexpr int STCV_NWG = G_STATS + G_PKEMB;
constexpr int NSTRIPE = G_STATS * 256 / 25;     // 4096

__global__ __launch_bounds__(256) void k_stcv(const unsigned short* __restrict__ x_bf,
                                              const float* __restrict__ emb_ent,
                                              float* __restrict__ colsum,
                                              float* __restrict__ colsq,
                                              unsigned short* __restrict__ emb_pk) {
    int blk = blockIdx.x, t = threadIdx.x;
    if (blk < G_STATS) {
        __shared__ float lsum[200], lsq[200];
        for (int i = t; i < 200; i += 256) { lsum[i] = 0.f; lsq[i] = 0.f; }
        __syncthreads();
        int gid = blk * 256 + t;          // 102400 = 25 col-groups x 4096 stripes
        int col8 = gid % 25;
        int stripe = gid / 25;
        float s[8] = {}, sq[8] = {};
        for (int r = stripe; r < V; r += NSTRIPE) {
            ushort8 xv = *(const ushort8*)&x_bf[(size_t)r * OUT + col8 * 8];
#pragma unroll
            for (int j = 0; j < 8; ++j) {
                float v = bf2f(xv[j]);
                s[j] += v;
                sq[j] += v * v;
            }
        }
#pragma unroll
        for (int j = 0; j < 8; ++j) {
            atomicAdd(&lsum[col8 * 8 + j], s[j]);
            atomicAdd(&lsq[col8 * 8 + j], sq[j]);
        }
        __syncthreads();
        for (int i = t; i < 200; i += 256) {
            atomicAdd(&colsum[i], lsum[i]);
            atomicAdd(&colsq[i], lsq[i]);
        }
    } else {
        int i = (blk - G_STATS) * 256 + t;
        if (i >= NTILE * 448) return;
        int vt = i / 448, r = i - vt * 448;
        int lane = r & 63;
        int ks = r >> 6;
        int v = vt * 16 + (lane & 15);
        int k0 = ks * 32 + (lane >> 4) * 8;
        ushort8 o = (ushort8)0;
        if (v < V && k0 < 200) {
            float4 f0 = *(const float4*)&emb_ent[(size_t)v * OUT + k0];
            float4 f1 = *(const float4*)&emb_ent[(size_t)v * OUT + k0 + 4];
            o[0] = f2bf(f0.x); o[1] = f2bf(f0.y); o[2] = f2bf(f0.z); o[3] = f2bf(f0.w);
            o[4] = f2bf(f1.x); o[5] = f2bf(f1.y); o[6] = f2bf(f1.z); o[7] = f2bf(f1.w);
        }
        *(ushort8*)&emb_pk[(size_t)i * 8] = o;
    }
}

// ---------------- obj_bf (inline mean/rstd; reads bf16 x)
__global__ __launch_bounds__(256) void k_obj(const int* __restrict__ head,
                                             const int* __restrict__ rela,
                                             const unsigned short* __restrict__ x_bf,
                                             const float* __restrict__ colsum,
                                             const float* __restrict__ colsq,
                                             const float* __restrict__ gamma,
                                             const float* __restrict__ beta,
                                             const float* __restrict__ r_out,
                                             unsigned short* __restrict__ obj_bf) {
    int b = blockIdx.x, t = threadIdx.x;
    if (t >= K2) return;
    float v = 0.f;
    if (t < OUT) {
        float m = colsum[t] / (float)V;
        float var = colsq[t] / (float)V - m * m;
        float rs = rsqrtf(var + EPS);
        int h = head[b], r = rela[b];
        float val = (bf2f(x_bf[(size_t)h * OUT + t]) - m) * rs * gamma[t] + beta[t];
        val = tanhf(val);
        v = val * r_out[r * OUT + t];
    }
    obj_bf[(size_t)b * K2 + t] = f2bf(v);
}

// ---------------- decoder: LDS-free MFMA GEMM, B from fragment-packed emb
constexpr int DEC_BM = 64, DEC_BN = 256;
constexpr int DEC_GX = B / DEC_BM;          // 16
constexpr int DEC_GY = VPAD / DEC_BN;       // 196
constexpr int DEC_NWG = DEC_GX * DEC_GY;    // 3136 (div by 8)

__global__ __launch_bounds__(256) void k_dec2(const unsigned short* __restrict__ obj_bf,
                                              const unsigned short* __restrict__ emb_pk,
                                              const float* __restrict__ ent_bias,
                                              float* __restrict__ score) {
    int t = threadIdx.x;
    int lane = t & 63, wid = t >> 6;
    int wg = (blockIdx.x & 7) * (DEC_NWG >> 3) + (blockIdx.x >> 3);
    int b0 = (wg & (DEC_GX - 1)) * DEC_BM;
    int v0 = (wg >> 4) * DEC_BN;
    int r16 = lane & 15;
    int kc = (lane >> 4) * 8;
    int vbase = v0 + wid * 64;
    int vtbase = vbase >> 4;
    const unsigned short* gA = obj_bf + (size_t)(b0 + r16) * K2 + kc;
    f32x4 acc[4][4] = {};
    for (int ks = 0; ks < 7; ++ks) {
        int kof = ks * 32;
        bf16x8 a[4], bb[4];
#pragma unroll
        for (int mf = 0; mf < 4; ++mf)
            a[mf] = *(const bf16x8*)(gA + (size_t)(mf * 16) * K2 + kof);
#pragma unroll
        for (int nf = 0; nf < 4; ++nf)
            bb[nf] = *(const bf16x8*)&emb_pk[(((size_t)(vtbase + nf) * 7 + ks) * 64 + lane) * 8];
#pragma unroll
        for (int mf = 0; mf < 4; ++mf)
#pragma unroll
            for (int nf = 0; nf < 4; ++nf)
                acc[mf][nf] = __builtin_amdgcn_mfma_f32_16x16x32_bf16(a[mf], bb[nf],
                                                                      acc[mf][nf], 0, 0, 0);
    }
#pragma unroll
    for (int nf = 0; nf < 4; ++nf) {
        int v = vbase + nf * 16 + r16;
        if (v >= V) continue;
        float bias = ent_bias[v];
#pragma unroll
        for (int mf = 0; mf < 4; ++mf) {
            int brow = b0 + mf * 16 + (lane >> 4) * 4;
            f32x4 av = acc[mf][nf];
#pragma unroll
            for (int i = 0; i < 4; ++i) {
                float val = av[i] + bias;
                score[(size_t)(brow + i) * V + v] = 1.f / (1.f + __expf(-val));
            }
        }
    }
}

extern "C" void kernel_launch(void* const* d_in, const int* in_sizes, int n_in,
                              void* d_out, int out_size, void* d_ws, size_t ws_size,
                              hipStream_t stream) {
    const int*   edge_src  = (const int*)d_in[0];
    const int*   edge_dst  = (const int*)d_in[1];
    const int*   edge_type = (const int*)d_in[2];
    const int*   head      = (const int*)d_in[3];
    const int*   rela      = (const int*)d_in[4];
    const float* edge_norm = (const float*)d_in[5];
    const float* ent_emb   = (const float*)d_in[6];
    const float* rel_emb   = (const float*)d_in[7];
    const float* in_w      = (const float*)d_in[8];
    const float* out_w     = (const float*)d_in[9];
    const float* loop_w    = (const float*)d_in[10];
    const float* w_rel     = (const float*)d_in[11];
    const float* loop_rel  = (const float*)d_in[12];
    const float* conv_bias = (const float*)d_in[13];
    const float* bn_gamma  = (const float*)d_in[14];
    const float* bn_beta   = (const float*)d_in[15];
    const float* emb_ent   = (const float*)d_in[16];
    const float* ent_bias  = (const float*)d_in[17];
    float* score = (float*)d_out;

    // ---- workspace layout
    char* w = (char*)d_ws;
    char*           base0  = w;                              w += (size_t)V * OUT * 4;   // 40 MB region
    unsigned short* Mtab   = (unsigned short*)w;             w += (size_t)NKEY * MT_SZ * 2;  // 42.6 MB
    unsigned*       perm1  = (unsigned*)w;                   w += (size_t)E1MAX * 4;
    int*            poslist  = (int*)w;                      w += (size_t)E * 4;
    uint2*          pairs    = (uint2*)w;                    w += (size_t)NB2 * BCAP * 8;
    char* zbase = w;
    int*   hist1     = (int*)w;                              w += NKEY * 4;
    int*   cursor1   = (int*)w;                              w += NKEY * 4;
    int*   cursor196 = (int*)w;                              w += NB2 * 4;
    float* colsum    = (float*)w;                            w += OUT * 4;
    float* colsq     = (float*)w;                            w += OUT * 4;
    size_t zbytes = (size_t)(w - zbase);
    int*   start1  = (int*)w;                                w += (NKEY + 1) * 4;
    int*   start2  = (int*)w;                                w += (V + 4) * 4;
    int*   Edev    = (int*)w;                                w += 16;
    float* Mloop   = (float*)w;                              w += (size_t)D * OUT * 4;
    float* r_out   = (float*)w;                              w += (size_t)R * OUT * 4;
    unsigned short* obj_bf = (unsigned short*)w;             w += (size_t)B * K2 * 2;
    unsigned short* WT_bf  = (unsigned short*)w;             w += (size_t)2 * 208 * 128 * 2;
    // overlays (strictly stream-ordered):
    unsigned short* ent_bf = (unsigned short*)base0; // V*128 ushorts; dead after k_edgemm
    unsigned short* x_bf   = (unsigned short*)base0; // V*200 ushorts; written by k_aggx (after k_edgemm)
    unsigned short* emb_pk = (unsigned short*)Mtab;  // NTILE*448*8 ushorts; Mtab dead after k_edgemm
    unsigned short* msg    = (unsigned short*)d_out; // E1MAX*200 ushorts; dead after k_aggx

    (void)hipMemsetAsync(zbase, 0, zbytes, stream);

    k_pre<<<PRE_NWG, 256, 0, stream>>>(loop_rel, loop_w, rel_emb, w_rel, in_w, out_w,
                                       ent_emb, edge_type, Mloop, r_out, WT_bf, ent_bf,
                                       hist1);
    k_scan<<<1, 1024, 0, stream>>>(hist1, start1, Edev, perm1);
    k_bin<<<(E + BIN_EPB - 1) / BIN_EPB, BIN_THREADS, 0, stream>>>(
        edge_type, edge_dst, start1, cursor1, cursor196, perm1, pairs);
    k_bd2mt<<<BD2MT_NWG, 256, 0, stream>>>(cursor196, pairs, rel_emb, WT_bf,
                                           start2, poslist, Mtab);
    k_edgemm<<<E1MAX / 64 / ECHK, 256, 0, stream>>>(perm1, Edev, edge_src, edge_norm,
                                                    ent_bf, Mtab, msg);
    k_aggx<<<V / 16, 256, 0, stream>>>(start2, poslist, msg, ent_emb, Mloop,
                                       conv_bias, x_bf);
    k_stcv<<<STCV_NWG, 256, 0, stream>>>(x_bf, emb_ent, colsum, colsq, emb_pk);
    k_obj<<<B, 256, 0, stream>>>(head, rela, x_bf, colsum, colsq, bn_gamma, bn_beta,
                                 r_out, obj_bf);
    k_dec2<<<DEC_NWG, 256, 0, stream>>>(obj_bf, emb_pk, ent_bias, score);
}